// Round 6
// baseline (707.448 us; speedup 1.0000x reference)
//
#include <hip/hip_runtime.h>
#include <hip/hip_bf16.h>

#define U_CNT 200000
#define I_CNT 100000
#define N_CNT 300000
#define E_CNT 1000000
#define ATTR_D 8
#define H_DIM 32
#define NB_SCAN ((N_CNT + 255) / 256)
#define NB_E4 ((E_CNT / 4 + 255) / 256)      // 977 blocks, 4 edges/thread
#define IB 128                               // items per item-block
#define NB_I ((I_CNT + IB - 1) / IB)         // 782 item blocks

// NOTE (rounds 1-4): all float inputs and the output are FLOAT32. absmax floor
// 1.95e-3 == bf16 rounding of the *reference*; threshold 1.26e-2.
// NOTE (round 7): rank-capture scatter (no cursor atomics) + y-space reform
// (y = dis*x; l2norm scale-invariant). 1098 -> 951 us.
// NOTE (round 8): k_items register-blocked LDS GEMM. 951 -> 886 us.
// NOTE (round 9): bf16 y-storage. FETCH halved but only -9% -> latency-bound.
// NOTE (round 10): k_prop 4 nodes/wave, 16 lanes/node (4x in-flight gathers).
// 830 -> 634 us, matched. Scattered-request kernels = latency x concurrency.
// NOTE (round 11): k_front fusion REGRESSED (634->643): 51KB LDS capped edge
// blocks at 3/CU, throttling atomic concurrency. Lesson: don't co-resident a
// latency-bound role with a big-LDS role. bf16 items math verified OK.
// NOTE (round 12, this round): revert fusion; apply the round-10 lever
// (in-flight requests per wave) to the scattered-request kernels instead:
// edge_mlp and scatter at 4 edges/thread (8 atomics / 8 stores in flight).
// Items keeps the bf16-LDS 4x8-tile design standalone.

typedef unsigned short ubf;

__device__ __forceinline__ float b2f(ubf b) {
    return __uint_as_float((unsigned)b << 16);
}
__device__ __forceinline__ ubf f2b(float v) {
    unsigned u = __float_as_uint(v);
    u += 0x7fffu + ((u >> 16) & 1u);           // round to nearest even
    return (ubf)(u >> 16);
}
__device__ __forceinline__ unsigned pk2(float lo, float hi) {
    return (unsigned)f2b(lo) | ((unsigned)f2b(hi) << 16);
}
__device__ __forceinline__ float4 b4f(ushort4 u) {
    return make_float4(b2f(u.x), b2f(u.y), b2f(u.z), b2f(u.w));
}

// ---------------- edge MLP + histogram; 4 edges/thread, 8 atomics in flight ----------------
__global__ void k_edge_mlp(const int* __restrict__ src, const int* __restrict__ dst,
                           const float* __restrict__ attr,
                           const float* __restrict__ W1, const float* __restrict__ b1,
                           const float* __restrict__ W2, const float* __restrict__ b2,
                           int2* __restrict__ wr, int* __restrict__ cnt) {
    __shared__ float sW1[ATTR_D * H_DIM];
    __shared__ float sb1[H_DIM];
    __shared__ float sW2[H_DIM];
    __shared__ float sb2;
    int t = threadIdx.x;
    sW1[t] = W1[t];                      // blockDim==256==ATTR_D*H_DIM
    if (t < H_DIM) { sb1[t] = b1[t]; sW2[t] = W2[t]; }
    if (t == 0) sb2 = b2[0];
    __syncthreads();
    int e0 = (blockIdx.x * 256 + t) * 4;
    if (e0 >= E_CNT) return;             // 4 | E_CNT: no partial groups
    int4 s4 = *(const int4*)&src[e0];
    int4 d4 = *(const int4*)&dst[e0];
    const float4* a4 = (const float4*)attr + (size_t)e0 * 2;
    float wv[4];
    #pragma unroll
    for (int i = 0; i < 4; ++i) {
        float4 r0 = a4[i * 2 + 0];
        float4 r1 = a4[i * 2 + 1];
        float a[8] = {r0.x, r0.y, r0.z, r0.w, r1.x, r1.y, r1.z, r1.w};
        float z = sb2;
        #pragma unroll
        for (int h = 0; h < H_DIM; ++h) {
            float acc = sb1[h];
            #pragma unroll
            for (int k = 0; k < 8; ++k) acc = fmaf(a[k], sW1[k * H_DIM + h], acc);
            acc = fmaxf(acc, 0.0f);
            z = fmaf(acc, sW2[h], z);
        }
        float w = 1.0f / (1.0f + __expf(-z));
        wv[i] = fmaxf(w, 1e-6f);
    }
    int ss[4] = {s4.x, s4.y, s4.z, s4.w};
    int dd[4] = {U_CNT + d4.x, U_CNT + d4.y, U_CNT + d4.z, U_CNT + d4.w};
    int rs[4], rd[4];
    #pragma unroll
    for (int i = 0; i < 4; ++i) rs[i] = atomicAdd(&cnt[ss[i]], 1);
    #pragma unroll
    for (int i = 0; i < 4; ++i) rd[i] = atomicAdd(&cnt[dd[i]], 1);
    int4 o0 = make_int4(__float_as_int(wv[0]), rs[0] | (rd[0] << 16),
                        __float_as_int(wv[1]), rs[1] | (rd[1] << 16));
    int4 o1 = make_int4(__float_as_int(wv[2]), rs[2] | (rd[2] << 16),
                        __float_as_int(wv[3]), rs[3] | (rd[3] << 16));
    *(int4*)&wr[e0 + 0] = o0;
    *(int4*)&wr[e0 + 2] = o1;
}

// ---------------- exclusive scan of cnt -> offs (3 kernels) ----------------
__global__ void k_scan1(const int* __restrict__ cnt, int* __restrict__ incl,
                        int* __restrict__ bsums) {
    __shared__ int s[256];
    int t = threadIdx.x;
    int i = blockIdx.x * 256 + t;
    int v = (i < N_CNT) ? cnt[i] : 0;
    s[t] = v;
    __syncthreads();
    #pragma unroll
    for (int off = 1; off < 256; off <<= 1) {
        int x = (t >= off) ? s[t - off] : 0;
        __syncthreads();
        s[t] += x;
        __syncthreads();
    }
    if (i < N_CNT) incl[i] = s[t];
    if (t == 255) bsums[blockIdx.x] = s[255];
}

__global__ void k_scan2(const int* __restrict__ bsums, int* __restrict__ bbase, int nb) {
    __shared__ int s[256];
    __shared__ int carry_s;
    int t = threadIdx.x;
    if (t == 0) carry_s = 0;
    __syncthreads();
    for (int start = 0; start < nb; start += 256) {
        int i = start + t;
        int v = (i < nb) ? bsums[i] : 0;
        s[t] = v;
        __syncthreads();
        #pragma unroll
        for (int off = 1; off < 256; off <<= 1) {
            int x = (t >= off) ? s[t - off] : 0;
            __syncthreads();
            s[t] += x;
            __syncthreads();
        }
        int carry = carry_s;
        if (i < nb) bbase[i] = carry + s[t] - v;  // exclusive
        __syncthreads();
        if (t == 255) carry_s += s[255];
        __syncthreads();
    }
}

__global__ void k_scan3(const int* __restrict__ incl, const int* __restrict__ cnt,
                        const int* __restrict__ bbase, int* __restrict__ offs) {
    int i = blockIdx.x * 256 + threadIdx.x;
    if (i < N_CNT) offs[i] = bbase[blockIdx.x] + incl[i] - cnt[i];
    if (i == 0) offs[N_CNT] = 2 * E_CNT;
}

// ---------------- scatter into CSR; 4 edges/thread, 8 stores in flight ----------------
__global__ void k_scatter(const int* __restrict__ src, const int* __restrict__ dst,
                          const int2* __restrict__ wr, const int* __restrict__ offs,
                          int2* __restrict__ csr) {
    int e0 = (blockIdx.x * 256 + threadIdx.x) * 4;
    if (e0 >= E_CNT) return;
    int4 s4 = *(const int4*)&src[e0];
    int4 d4 = *(const int4*)&dst[e0];
    int4 w0 = *(const int4*)&wr[e0 + 0];
    int4 w1 = *(const int4*)&wr[e0 + 2];
    int ss[4] = {s4.x, s4.y, s4.z, s4.w};
    int dd[4] = {U_CNT + d4.x, U_CNT + d4.y, U_CNT + d4.z, U_CNT + d4.w};
    int wv[4] = {w0.x, w0.z, w1.x, w1.z};
    unsigned rk[4] = {(unsigned)w0.y, (unsigned)w0.w, (unsigned)w1.y, (unsigned)w1.w};
    int os[4], od[4];
    #pragma unroll
    for (int i = 0; i < 4; ++i) os[i] = offs[ss[i]];
    #pragma unroll
    for (int i = 0; i < 4; ++i) od[i] = offs[dd[i]];
    #pragma unroll
    for (int i = 0; i < 4; ++i) {
        csr[os[i] + (rk[i] & 0xffffu)] = make_int2(dd[i], wv[i]);
        csr[od[i] + (rk[i] >> 16)]     = make_int2(ss[i], wv[i]);
    }
}

// ---------------- deg via segment sum (no atomics), dis = rsqrt(1+sum) ----------------
__global__ void k_deg(const int* __restrict__ offs, const int2* __restrict__ csr,
                      float* __restrict__ dis) {
    int i = blockIdx.x * 256 + threadIdx.x;
    if (i >= N_CNT) return;
    int b = offs[i], e = offs[i + 1];
    float s = 1.0f;                      // self loop weight
    for (int k = b; k < e; ++k) s += __int_as_float(csr[k].y);
    dis[i] = rsqrtf(s);                  // s >= 1 always
}

// ---------------- users: y0 = dis * l2norm(user_w) ----------------
__global__ void k_users(const float* __restrict__ user_w, const float* __restrict__ dis,
                        ubf* __restrict__ y0, float* __restrict__ acc, int use_acc) {
    int lane = threadIdx.x & 63;
    int wv = (blockIdx.x * blockDim.x + threadIdx.x) >> 6;
    int nw = (gridDim.x * blockDim.x) >> 6;
    for (int r = wv; r < U_CNT; r += nw) {
        int idx = r * 64 + lane;
        float v = user_w[idx];
        float ss = v * v;
        #pragma unroll
        for (int m = 32; m >= 1; m >>= 1) ss += __shfl_xor(ss, m, 64);
        float inv = dis[r] / fmaxf(sqrtf(ss), 1e-12f);
        float o = v * inv;
        y0[idx] = f2b(o);
        if (use_acc) acc[idx] = o;
    }
}

// ---------------- items: bf16-LDS GEMM, 4 items x 8 outs per thread ----------------
// sXT [128 f][136 item-pitch] bf16 + sW [128 k][64 d] bf16 = 50.8 KB
__global__ void __launch_bounds__(256)
k_items(const float* __restrict__ audio, const float* __restrict__ art,
        const float* __restrict__ alb, const int* __restrict__ aid,
        const int* __restrict__ alid, const float* __restrict__ Wp,
        const float* __restrict__ bp, const float* __restrict__ dis,
        ubf* __restrict__ yitem, float* __restrict__ accitem, int use_acc) {
    __shared__ __align__(16) ubf shm[128 * 136 + 128 * 64];
    int t = threadIdx.x;
    int base = blockIdx.x * IB;
    ubf* sXT = shm;
    ubf* sW  = shm + 128 * 136;
    // stage Wp -> bf16
    {
        const float4* wg = (const float4*)Wp;
        #pragma unroll
        for (int r = 0; r < 8; ++r) {
            int idx = r * 256 + t;
            float4 v = wg[idx];
            ushort4 o = make_ushort4(f2b(v.x), f2b(v.y), f2b(v.z), f2b(v.w));
            *(ushort4*)&sW[idx * 4] = o;
        }
    }
    // stage audio -> sXT[f][i] transposed
    {
        const float4* g = (const float4*)audio + (size_t)base * 16;
        #pragma unroll
        for (int r = 0; r < 8; ++r) {
            int idx = r * 256 + t;               // 0..2047
            int i = idx >> 4, fq = idx & 15;
            float4 v = make_float4(0.f, 0.f, 0.f, 0.f);
            if (base + i < I_CNT) v = g[idx];
            sXT[(4 * fq + 0) * 136 + i] = f2b(v.x);
            sXT[(4 * fq + 1) * 136 + i] = f2b(v.y);
            sXT[(4 * fq + 2) * 136 + i] = f2b(v.z);
            sXT[(4 * fq + 3) * 136 + i] = f2b(v.w);
        }
    }
    // stage meta -> sXT[64+f][i]
    {
        int lane = t & 63, wv = t >> 6;
        for (int i = wv; i < IB; i += 4) {
            int it = base + i;
            float v = 0.f;
            if (it < I_CNT) {
                int a_ = aid[it], al_ = alid[it];
                v = art[a_ * 64 + lane] + alb[al_ * 64 + lane];
            }
            sXT[(64 + lane) * 136 + i] = f2b(v);
        }
    }
    __syncthreads();
    int og = t & 7;                      // outs 8og..8og+7
    int igr = t >> 3;                    // items 4igr..4igr+3
    float c[4][8];
    {
        float bv[8];
        #pragma unroll
        for (int j = 0; j < 8; ++j) bv[j] = bp[8 * og + j];
        #pragma unroll
        for (int i = 0; i < 4; ++i)
            #pragma unroll
            for (int j = 0; j < 8; ++j) c[i][j] = bv[j];
    }
    const ubf* xcol = &sXT[4 * igr];
    const ubf* wrow = &sW[8 * og];
    #pragma unroll 2
    for (int k = 0; k < 128; ++k) {
        ushort4 xu = *(const ushort4*)&xcol[k * 136];
        uint4 wu = *(const uint4*)&wrow[k * 64];
        float x[4] = {b2f(xu.x), b2f(xu.y), b2f(xu.z), b2f(xu.w)};
        float w[8];
        w[0] = __uint_as_float(wu.x << 16); w[1] = __uint_as_float(wu.x & 0xffff0000u);
        w[2] = __uint_as_float(wu.y << 16); w[3] = __uint_as_float(wu.y & 0xffff0000u);
        w[4] = __uint_as_float(wu.z << 16); w[5] = __uint_as_float(wu.z & 0xffff0000u);
        w[6] = __uint_as_float(wu.w << 16); w[7] = __uint_as_float(wu.w & 0xffff0000u);
        #pragma unroll
        for (int i = 0; i < 4; ++i)
            #pragma unroll
            for (int j = 0; j < 8; ++j) c[i][j] = fmaf(x[i], w[j], c[i][j]);
    }
    #pragma unroll
    for (int i = 0; i < 4; ++i) {
        float ss = 0.f;
        #pragma unroll
        for (int j = 0; j < 8; ++j) ss += c[i][j] * c[i][j];
        ss += __shfl_xor(ss, 1, 64);
        ss += __shfl_xor(ss, 2, 64);
        ss += __shfl_xor(ss, 4, 64);
        int it = base + 4 * igr + i;
        if (it < I_CNT) {
            float q = dis[U_CNT + it] / fmaxf(sqrtf(ss), 1e-12f);
            uint4 o;
            o.x = pk2(c[i][0] * q, c[i][1] * q);
            o.y = pk2(c[i][2] * q, c[i][3] * q);
            o.z = pk2(c[i][4] * q, c[i][5] * q);
            o.w = pk2(c[i][6] * q, c[i][7] * q);
            *(uint4*)&yitem[(size_t)it * 64 + 8 * og] = o;
            if (use_acc) {
                float4* ap = (float4*)&accitem[(size_t)it * 64 + 8 * og];
                ap[0] = make_float4(c[i][0] * q, c[i][1] * q, c[i][2] * q, c[i][3] * q);
                ap[1] = make_float4(c[i][4] * q, c[i][5] * q, c[i][6] * q, c[i][7] * q);
            }
        }
    }
}

// ---------------- LGConv round: 4 nodes/wave, 16 lanes/node, ushort4/lane ----------------
__global__ void k_prop(const int* __restrict__ offs, const int2* __restrict__ csr,
                       const float* __restrict__ dis,
                       const ubf* __restrict__ yin, ubf* __restrict__ yout,
                       float* __restrict__ acc, int use_acc) {
    int lane = threadIdx.x & 63;
    int g = lane >> 4;                   // node group 0..3
    int s4 = (lane & 15) * 4;            // dims s4..s4+3
    int wv = (blockIdx.x * 256 + threadIdx.x) >> 6;
    int c = wv * 4 + g;
    if (c >= N_CNT) return;
    int e = offs[c], end = offs[c + 1];
    float dc = dis[c];
    float4 a0 = make_float4(0.f, 0.f, 0.f, 0.f);
    float4 a1 = a0, a2 = a0, a3 = a0;
    for (; e + 3 < end; e += 4) {
        int2 e0 = csr[e], e1 = csr[e + 1], e2 = csr[e + 2], e3 = csr[e + 3];
        ushort4 g0 = *(const ushort4*)&yin[(size_t)e0.x * 64 + s4];
        ushort4 g1 = *(const ushort4*)&yin[(size_t)e1.x * 64 + s4];
        ushort4 g2 = *(const ushort4*)&yin[(size_t)e2.x * 64 + s4];
        ushort4 g3 = *(const ushort4*)&yin[(size_t)e3.x * 64 + s4];
        float w0 = __int_as_float(e0.y), w1 = __int_as_float(e1.y);
        float w2 = __int_as_float(e2.y), w3 = __int_as_float(e3.y);
        float4 f0 = b4f(g0), f1 = b4f(g1), f2 = b4f(g2), f3 = b4f(g3);
        a0.x = fmaf(w0, f0.x, a0.x); a0.y = fmaf(w0, f0.y, a0.y);
        a0.z = fmaf(w0, f0.z, a0.z); a0.w = fmaf(w0, f0.w, a0.w);
        a1.x = fmaf(w1, f1.x, a1.x); a1.y = fmaf(w1, f1.y, a1.y);
        a1.z = fmaf(w1, f1.z, a1.z); a1.w = fmaf(w1, f1.w, a1.w);
        a2.x = fmaf(w2, f2.x, a2.x); a2.y = fmaf(w2, f2.y, a2.y);
        a2.z = fmaf(w2, f2.z, a2.z); a2.w = fmaf(w2, f2.w, a2.w);
        a3.x = fmaf(w3, f3.x, a3.x); a3.y = fmaf(w3, f3.y, a3.y);
        a3.z = fmaf(w3, f3.z, a3.z); a3.w = fmaf(w3, f3.w, a3.w);
    }
    for (; e < end; ++e) {
        int2 ee = csr[e];
        ushort4 gg = *(const ushort4*)&yin[(size_t)ee.x * 64 + s4];
        float ww = __int_as_float(ee.y);
        float4 ff = b4f(gg);
        a0.x = fmaf(ww, ff.x, a0.x); a0.y = fmaf(ww, ff.y, a0.y);
        a0.z = fmaf(ww, ff.z, a0.z); a0.w = fmaf(ww, ff.w, a0.w);
    }
    size_t idx = (size_t)c * 64 + s4;
    float4 self = b4f(*(const ushort4*)&yin[idx]);
    float dc2 = dc * dc;
    float4 r;
    r.x = dc2 * (((a0.x + a1.x) + (a2.x + a3.x)) + self.x);
    r.y = dc2 * (((a0.y + a1.y) + (a2.y + a3.y)) + self.y);
    r.z = dc2 * (((a0.z + a1.z) + (a2.z + a3.z)) + self.z);
    r.w = dc2 * (((a0.w + a1.w) + (a2.w + a3.w)) + self.w);
    *(ushort4*)&yout[idx] = make_ushort4(f2b(r.x), f2b(r.y), f2b(r.z), f2b(r.w));
    if (use_acc) {
        float4* ap = (float4*)&acc[idx];
        float4 av = *ap;
        av.x += r.x; av.y += r.y; av.z += r.z; av.w += r.w;
        *ap = av;
    }
}

// ---------------- epilogue A: l2norm(acc)  (acc fp32, may alias out) ----------------
__global__ void k_final_acc(const float* __restrict__ acc, float* __restrict__ out) {
    int lane = threadIdx.x & 63;
    int c = (blockIdx.x * 256 + threadIdx.x) >> 6;
    if (c >= N_CNT) return;
    int idx = c * 64 + lane;
    float v = acc[idx];
    float ss = v * v;
    #pragma unroll
    for (int m = 32; m >= 1; m >>= 1) ss += __shfl_xor(ss, m, 64);
    out[idx] = v / fmaxf(sqrtf(ss), 1e-12f);
}

// ---------------- epilogue B: l2norm(y0+y1+y2+y3), all bf16 ----------------
__global__ void k_final_sum(const ubf* __restrict__ y0, const ubf* __restrict__ y1,
                            const ubf* __restrict__ y2, const ubf* __restrict__ y3,
                            float* __restrict__ out) {
    int lane = threadIdx.x & 63;
    int c = (blockIdx.x * 256 + threadIdx.x) >> 6;
    if (c >= N_CNT) return;
    int idx = c * 64 + lane;
    float v = b2f(y0[idx]) + b2f(y1[idx]) + b2f(y2[idx]) + b2f(y3[idx]);
    float ss = v * v;
    #pragma unroll
    for (int m = 32; m >= 1; m >>= 1) ss += __shfl_xor(ss, m, 64);
    out[idx] = v / fmaxf(sqrtf(ss), 1e-12f);
}

extern "C" void kernel_launch(void* const* d_in, const int* in_sizes, int n_in,
                              void* d_out, int out_size, void* d_ws, size_t ws_size,
                              hipStream_t stream) {
    const int*   edge_src   = (const int*)  d_in[0];
    const int*   edge_dst   = (const int*)  d_in[1];
    const float* edge_attr  = (const float*)d_in[2];
    const float* user_w     = (const float*)d_in[3];
    const float* artist_w   = (const float*)d_in[4];
    const float* album_w    = (const float*)d_in[5];
    const float* item_audio = (const float*)d_in[6];
    const int*   artist_ids = (const int*)  d_in[7];
    const int*   album_ids  = (const int*)  d_in[8];
    const float* Wp         = (const float*)d_in[9];
    const float* bp         = (const float*)d_in[10];
    const float* W1         = (const float*)d_in[11];
    const float* b1         = (const float*)d_in[12];
    const float* W2         = (const float*)d_in[13];
    const float* b2         = (const float*)d_in[14];

    char* p = (char*)d_ws;
    auto carve = [&](size_t bytes) -> void* {
        void* q = (void*)p;
        p += (bytes + 255) & ~(size_t)255;
        return q;
    };
    // common carve (~28 MB)
    float* dis    = (float*)carve((size_t)N_CNT * 4);
    int2*  wr     = (int2*) carve((size_t)E_CNT * 8);       // {w, rank_s|rank_d<<16}
    int*   cnt    = (int*)  carve((size_t)N_CNT * 4);
    int*   offs   = (int*)  carve((size_t)(N_CNT + 1) * 4);
    int*   incl   = (int*)  carve((size_t)N_CNT * 4);
    int*   bsums  = (int*)  carve((size_t)NB_SCAN * 4);
    int*   bbase  = (int*)  carve((size_t)NB_SCAN * 4);
    int2*  csr    = (int2*) carve((size_t)2 * E_CNT * 8);
    const size_t YB = (size_t)N_CNT * 64 * 2;      // 38.4 MB per bf16 y buffer
    size_t used = (size_t)(p - (char*)d_ws);
    // Path B (no acc RMW) needs y0..y3 bf16 in ws; else ping-pong + fp32 acc in d_out.
    int no_acc = (ws_size >= used + 4 * YB + (size_t)4096) ? 1 : 0;
    ubf *y0, *y1, *y2, *y3;
    float* acc = nullptr;
    if (no_acc) {
        y0 = (ubf*)carve(YB);
        y1 = (ubf*)carve(YB);
        y2 = (ubf*)carve(YB);
        y3 = (ubf*)carve(YB);
    } else {
        y0 = (ubf*)carve(YB);
        y1 = (ubf*)carve(YB);
        y2 = y0;
        y3 = y1;
        acc = (float*)d_out;           // fp32 accumulator lives in d_out
    }
    (void)in_sizes; (void)n_in; (void)out_size;

    hipMemsetAsync(cnt, 0, (size_t)N_CNT * 4, stream);
    k_edge_mlp<<<NB_E4, 256, 0, stream>>>(edge_src, edge_dst, edge_attr,
                                          W1, b1, W2, b2, wr, cnt);
    k_scan1  <<<NB_SCAN, 256, 0, stream>>>(cnt, incl, bsums);
    k_scan2  <<<1, 256, 0, stream>>>(bsums, bbase, NB_SCAN);
    k_scan3  <<<NB_SCAN, 256, 0, stream>>>(incl, cnt, bbase, offs);
    k_scatter<<<NB_E4, 256, 0, stream>>>(edge_src, edge_dst, wr, offs, csr);
    k_deg    <<<NB_SCAN, 256, 0, stream>>>(offs, csr, dis);
    k_users  <<<1024, 256, 0, stream>>>(user_w, dis, y0, acc, no_acc ? 0 : 1);
    k_items  <<<NB_I, 256, 0, stream>>>(item_audio, artist_w, album_w,
                                        artist_ids, album_ids, Wp, bp, dis,
                                        y0 + (size_t)U_CNT * 64,
                                        no_acc ? nullptr : acc + (size_t)U_CNT * 64,
                                        no_acc ? 0 : 1);
    // 4 nodes per wave -> N/4 waves -> N/16 blocks of 256
    const int PROP_BLKS = N_CNT / 16;    // 18750
    if (no_acc) {
        k_prop<<<PROP_BLKS, 256, 0, stream>>>(offs, csr, dis, y0, y1, nullptr, 0);
        k_prop<<<PROP_BLKS, 256, 0, stream>>>(offs, csr, dis, y1, y2, nullptr, 0);
        k_prop<<<PROP_BLKS, 256, 0, stream>>>(offs, csr, dis, y2, y3, nullptr, 0);
        k_final_sum<<<N_CNT / 4, 256, 0, stream>>>(y0, y1, y2, y3, (float*)d_out);
    } else {
        // y0 -> y1 -> y0 -> y1 (bf16), accumulating fp32 into acc (= d_out)
        k_prop<<<PROP_BLKS, 256, 0, stream>>>(offs, csr, dis, y0, y1, acc, 1);
        k_prop<<<PROP_BLKS, 256, 0, stream>>>(offs, csr, dis, y1, y0, acc, 1);
        k_prop<<<PROP_BLKS, 256, 0, stream>>>(offs, csr, dis, y0, y1, acc, 1);
        k_final_acc<<<N_CNT / 4, 256, 0, stream>>>(acc, (float*)d_out);
    }
}

// Round 7
// 635.377 us; speedup vs baseline: 1.1134x; 1.1134x over previous
//
#include <hip/hip_runtime.h>
#include <hip/hip_bf16.h>

#define U_CNT 200000
#define I_CNT 100000
#define N_CNT 300000
#define E_CNT 1000000
#define ATTR_D 8
#define H_DIM 32
#define NB_SCAN ((N_CNT + 255) / 256)
#define NB_E ((E_CNT + 255) / 256)
#define IB 128                               // items per item-block
#define NB_I ((I_CNT + IB - 1) / IB)         // 782 item blocks

// NOTE (rounds 1-4): all float inputs and the output are FLOAT32. absmax floor
// 1.95e-3 == bf16 rounding of the *reference*; threshold 1.26e-2.
// NOTE (round 7): rank-capture scatter (no cursor atomics) + y-space reform
// (y = dis*x; l2norm scale-invariant). 1098 -> 951 us.
// NOTE (round 8): k_items register-blocked LDS GEMM. 951 -> 886 us.
// NOTE (round 9): bf16 y-storage. FETCH halved but only -9% -> latency-bound.
// NOTE (round 10): k_prop 4 nodes/wave, 16 lanes/node (4x in-flight gathers).
// 830 -> 634 us, matched. GATHER kernels = latency x concurrency.
// NOTE (round 11): k_front fusion REGRESSED (51KB LDS throttled edge-atomic
// occupancy). Lesson: don't co-resident latency-bound role with big-LDS role.
// NOTE (round 12): 4-edges/thread batching REGRESSED for ATOMIC kernels
// (643->707): FETCH 19.5->214MB, WRITE 70->221MB (line-granular atomic
// traffic), occupancy 60->31% (977 blocks < fill). Lesson: scattered ATOMICS
// want many waves, not many per-wave requests — opposite of gathers.
// NOTE (round 13, this round): revert edge_mlp+scatter to 1-edge/thread
// (proven 92.6/~70us); keep standalone bf16-LDS k_items (round-12 version).

typedef unsigned short ubf;

__device__ __forceinline__ float b2f(ubf b) {
    return __uint_as_float((unsigned)b << 16);
}
__device__ __forceinline__ ubf f2b(float v) {
    unsigned u = __float_as_uint(v);
    u += 0x7fffu + ((u >> 16) & 1u);           // round to nearest even
    return (ubf)(u >> 16);
}
__device__ __forceinline__ unsigned pk2(float lo, float hi) {
    return (unsigned)f2b(lo) | ((unsigned)f2b(hi) << 16);
}
__device__ __forceinline__ float4 b4f(ushort4 u) {
    return make_float4(b2f(u.x), b2f(u.y), b2f(u.z), b2f(u.w));
}

// ---------------- edge MLP + count histogram; rank capture (1 edge/thread) ----------------
__global__ void k_edge_mlp(const int* __restrict__ src, const int* __restrict__ dst,
                           const float* __restrict__ attr,
                           const float* __restrict__ W1, const float* __restrict__ b1,
                           const float* __restrict__ W2, const float* __restrict__ b2,
                           int2* __restrict__ wr, int* __restrict__ cnt) {
    __shared__ float sW1[ATTR_D * H_DIM];
    __shared__ float sb1[H_DIM];
    __shared__ float sW2[H_DIM];
    __shared__ float sb2;
    int t = threadIdx.x;
    sW1[t] = W1[t];                      // blockDim==256==ATTR_D*H_DIM
    if (t < H_DIM) { sb1[t] = b1[t]; sW2[t] = W2[t]; }
    if (t == 0) sb2 = b2[0];
    __syncthreads();
    int e = blockIdx.x * 256 + t;
    if (e >= E_CNT) return;
    const float4* a4 = (const float4*)attr;     // 32B/row: two float4
    float4 r0 = a4[e * 2 + 0];
    float4 r1 = a4[e * 2 + 1];
    float a[8] = {r0.x, r0.y, r0.z, r0.w, r1.x, r1.y, r1.z, r1.w};
    float z = sb2;
    #pragma unroll
    for (int h = 0; h < H_DIM; ++h) {
        float acc = sb1[h];
        #pragma unroll
        for (int k = 0; k < 8; ++k) acc = fmaf(a[k], sW1[k * H_DIM + h], acc);
        acc = fmaxf(acc, 0.0f);
        z = fmaf(acc, sW2[h], z);
    }
    float w = 1.0f / (1.0f + __expf(-z));
    w = fmaxf(w, 1e-6f);
    int s = src[e], d = U_CNT + dst[e];
    int rs = atomicAdd(&cnt[s], 1);      // rank of e within node s's list
    int rd = atomicAdd(&cnt[d], 1);      // rank of e within node d's list
    wr[e] = make_int2(__float_as_int(w), rs | (rd << 16));   // deg << 65536
}

// ---------------- exclusive scan of cnt -> offs (3 kernels) ----------------
__global__ void k_scan1(const int* __restrict__ cnt, int* __restrict__ incl,
                        int* __restrict__ bsums) {
    __shared__ int s[256];
    int t = threadIdx.x;
    int i = blockIdx.x * 256 + t;
    int v = (i < N_CNT) ? cnt[i] : 0;
    s[t] = v;
    __syncthreads();
    #pragma unroll
    for (int off = 1; off < 256; off <<= 1) {
        int x = (t >= off) ? s[t - off] : 0;
        __syncthreads();
        s[t] += x;
        __syncthreads();
    }
    if (i < N_CNT) incl[i] = s[t];
    if (t == 255) bsums[blockIdx.x] = s[255];
}

__global__ void k_scan2(const int* __restrict__ bsums, int* __restrict__ bbase, int nb) {
    __shared__ int s[256];
    __shared__ int carry_s;
    int t = threadIdx.x;
    if (t == 0) carry_s = 0;
    __syncthreads();
    for (int start = 0; start < nb; start += 256) {
        int i = start + t;
        int v = (i < nb) ? bsums[i] : 0;
        s[t] = v;
        __syncthreads();
        #pragma unroll
        for (int off = 1; off < 256; off <<= 1) {
            int x = (t >= off) ? s[t - off] : 0;
            __syncthreads();
            s[t] += x;
            __syncthreads();
        }
        int carry = carry_s;
        if (i < nb) bbase[i] = carry + s[t] - v;  // exclusive
        __syncthreads();
        if (t == 255) carry_s += s[255];
        __syncthreads();
    }
}

__global__ void k_scan3(const int* __restrict__ incl, const int* __restrict__ cnt,
                        const int* __restrict__ bbase, int* __restrict__ offs) {
    int i = blockIdx.x * 256 + threadIdx.x;
    if (i < N_CNT) offs[i] = bbase[blockIdx.x] + incl[i] - cnt[i];
    if (i == 0) offs[N_CNT] = 2 * E_CNT;
}

// ---------------- scatter edges into CSR at offs[node]+rank (1 edge/thread) ----------------
__global__ void k_scatter(const int* __restrict__ src, const int* __restrict__ dst,
                          const int2* __restrict__ wr, const int* __restrict__ offs,
                          int2* __restrict__ csr) {
    int e = blockIdx.x * 256 + threadIdx.x;
    if (e >= E_CNT) return;
    int2 v = wr[e];
    unsigned rk = (unsigned)v.y;
    int s = src[e], d = U_CNT + dst[e];
    csr[offs[s] + (rk & 0xffffu)] = make_int2(d, v.x);   // row under s, partner d
    csr[offs[d] + (rk >> 16)]     = make_int2(s, v.x);   // row under d, partner s
}

// ---------------- deg via segment sum (no atomics), dis = rsqrt(1+sum) ----------------
__global__ void k_deg(const int* __restrict__ offs, const int2* __restrict__ csr,
                      float* __restrict__ dis) {
    int i = blockIdx.x * 256 + threadIdx.x;
    if (i >= N_CNT) return;
    int b = offs[i], e = offs[i + 1];
    float s = 1.0f;                      // self loop weight
    for (int k = b; k < e; ++k) s += __int_as_float(csr[k].y);
    dis[i] = rsqrtf(s);                  // s >= 1 always
}

// ---------------- users: y0 = dis * l2norm(user_w) ----------------
__global__ void k_users(const float* __restrict__ user_w, const float* __restrict__ dis,
                        ubf* __restrict__ y0, float* __restrict__ acc, int use_acc) {
    int lane = threadIdx.x & 63;
    int wv = (blockIdx.x * blockDim.x + threadIdx.x) >> 6;
    int nw = (gridDim.x * blockDim.x) >> 6;
    for (int r = wv; r < U_CNT; r += nw) {
        int idx = r * 64 + lane;
        float v = user_w[idx];
        float ss = v * v;
        #pragma unroll
        for (int m = 32; m >= 1; m >>= 1) ss += __shfl_xor(ss, m, 64);
        float inv = dis[r] / fmaxf(sqrtf(ss), 1e-12f);
        float o = v * inv;
        y0[idx] = f2b(o);
        if (use_acc) acc[idx] = o;
    }
}

// ---------------- items: bf16-LDS GEMM, 4 items x 8 outs per thread ----------------
// sXT [128 f][136 item-pitch] bf16 + sW [128 k][64 d] bf16 = 50.8 KB
__global__ void __launch_bounds__(256)
k_items(const float* __restrict__ audio, const float* __restrict__ art,
        const float* __restrict__ alb, const int* __restrict__ aid,
        const int* __restrict__ alid, const float* __restrict__ Wp,
        const float* __restrict__ bp, const float* __restrict__ dis,
        ubf* __restrict__ yitem, float* __restrict__ accitem, int use_acc) {
    __shared__ __align__(16) ubf shm[128 * 136 + 128 * 64];
    int t = threadIdx.x;
    int base = blockIdx.x * IB;
    ubf* sXT = shm;
    ubf* sW  = shm + 128 * 136;
    // stage Wp -> bf16
    {
        const float4* wg = (const float4*)Wp;
        #pragma unroll
        for (int r = 0; r < 8; ++r) {
            int idx = r * 256 + t;
            float4 v = wg[idx];
            ushort4 o = make_ushort4(f2b(v.x), f2b(v.y), f2b(v.z), f2b(v.w));
            *(ushort4*)&sW[idx * 4] = o;
        }
    }
    // stage audio -> sXT[f][i] transposed
    {
        const float4* g = (const float4*)audio + (size_t)base * 16;
        #pragma unroll
        for (int r = 0; r < 8; ++r) {
            int idx = r * 256 + t;               // 0..2047
            int i = idx >> 4, fq = idx & 15;
            float4 v = make_float4(0.f, 0.f, 0.f, 0.f);
            if (base + i < I_CNT) v = g[idx];
            sXT[(4 * fq + 0) * 136 + i] = f2b(v.x);
            sXT[(4 * fq + 1) * 136 + i] = f2b(v.y);
            sXT[(4 * fq + 2) * 136 + i] = f2b(v.z);
            sXT[(4 * fq + 3) * 136 + i] = f2b(v.w);
        }
    }
    // stage meta -> sXT[64+f][i]
    {
        int lane = t & 63, wv = t >> 6;
        for (int i = wv; i < IB; i += 4) {
            int it = base + i;
            float v = 0.f;
            if (it < I_CNT) {
                int a_ = aid[it], al_ = alid[it];
                v = art[a_ * 64 + lane] + alb[al_ * 64 + lane];
            }
            sXT[(64 + lane) * 136 + i] = f2b(v);
        }
    }
    __syncthreads();
    int og = t & 7;                      // outs 8og..8og+7
    int igr = t >> 3;                    // items 4igr..4igr+3
    float c[4][8];
    {
        float bv[8];
        #pragma unroll
        for (int j = 0; j < 8; ++j) bv[j] = bp[8 * og + j];
        #pragma unroll
        for (int i = 0; i < 4; ++i)
            #pragma unroll
            for (int j = 0; j < 8; ++j) c[i][j] = bv[j];
    }
    const ubf* xcol = &sXT[4 * igr];
    const ubf* wrow = &sW[8 * og];
    #pragma unroll 2
    for (int k = 0; k < 128; ++k) {
        ushort4 xu = *(const ushort4*)&xcol[k * 136];
        uint4 wu = *(const uint4*)&wrow[k * 64];
        float x[4] = {b2f(xu.x), b2f(xu.y), b2f(xu.z), b2f(xu.w)};
        float w[8];
        w[0] = __uint_as_float(wu.x << 16); w[1] = __uint_as_float(wu.x & 0xffff0000u);
        w[2] = __uint_as_float(wu.y << 16); w[3] = __uint_as_float(wu.y & 0xffff0000u);
        w[4] = __uint_as_float(wu.z << 16); w[5] = __uint_as_float(wu.z & 0xffff0000u);
        w[6] = __uint_as_float(wu.w << 16); w[7] = __uint_as_float(wu.w & 0xffff0000u);
        #pragma unroll
        for (int i = 0; i < 4; ++i)
            #pragma unroll
            for (int j = 0; j < 8; ++j) c[i][j] = fmaf(x[i], w[j], c[i][j]);
    }
    #pragma unroll
    for (int i = 0; i < 4; ++i) {
        float ss = 0.f;
        #pragma unroll
        for (int j = 0; j < 8; ++j) ss += c[i][j] * c[i][j];
        ss += __shfl_xor(ss, 1, 64);
        ss += __shfl_xor(ss, 2, 64);
        ss += __shfl_xor(ss, 4, 64);
        int it = base + 4 * igr + i;
        if (it < I_CNT) {
            float q = dis[U_CNT + it] / fmaxf(sqrtf(ss), 1e-12f);
            uint4 o;
            o.x = pk2(c[i][0] * q, c[i][1] * q);
            o.y = pk2(c[i][2] * q, c[i][3] * q);
            o.z = pk2(c[i][4] * q, c[i][5] * q);
            o.w = pk2(c[i][6] * q, c[i][7] * q);
            *(uint4*)&yitem[(size_t)it * 64 + 8 * og] = o;
            if (use_acc) {
                float4* ap = (float4*)&accitem[(size_t)it * 64 + 8 * og];
                ap[0] = make_float4(c[i][0] * q, c[i][1] * q, c[i][2] * q, c[i][3] * q);
                ap[1] = make_float4(c[i][4] * q, c[i][5] * q, c[i][6] * q, c[i][7] * q);
            }
        }
    }
}

// ---------------- LGConv round: 4 nodes/wave, 16 lanes/node, ushort4/lane ----------------
__global__ void k_prop(const int* __restrict__ offs, const int2* __restrict__ csr,
                       const float* __restrict__ dis,
                       const ubf* __restrict__ yin, ubf* __restrict__ yout,
                       float* __restrict__ acc, int use_acc) {
    int lane = threadIdx.x & 63;
    int g = lane >> 4;                   // node group 0..3
    int s4 = (lane & 15) * 4;            // dims s4..s4+3
    int wv = (blockIdx.x * 256 + threadIdx.x) >> 6;
    int c = wv * 4 + g;
    if (c >= N_CNT) return;
    int e = offs[c], end = offs[c + 1];
    float dc = dis[c];
    float4 a0 = make_float4(0.f, 0.f, 0.f, 0.f);
    float4 a1 = a0, a2 = a0, a3 = a0;
    for (; e + 3 < end; e += 4) {
        int2 e0 = csr[e], e1 = csr[e + 1], e2 = csr[e + 2], e3 = csr[e + 3];
        ushort4 g0 = *(const ushort4*)&yin[(size_t)e0.x * 64 + s4];
        ushort4 g1 = *(const ushort4*)&yin[(size_t)e1.x * 64 + s4];
        ushort4 g2 = *(const ushort4*)&yin[(size_t)e2.x * 64 + s4];
        ushort4 g3 = *(const ushort4*)&yin[(size_t)e3.x * 64 + s4];
        float w0 = __int_as_float(e0.y), w1 = __int_as_float(e1.y);
        float w2 = __int_as_float(e2.y), w3 = __int_as_float(e3.y);
        float4 f0 = b4f(g0), f1 = b4f(g1), f2 = b4f(g2), f3 = b4f(g3);
        a0.x = fmaf(w0, f0.x, a0.x); a0.y = fmaf(w0, f0.y, a0.y);
        a0.z = fmaf(w0, f0.z, a0.z); a0.w = fmaf(w0, f0.w, a0.w);
        a1.x = fmaf(w1, f1.x, a1.x); a1.y = fmaf(w1, f1.y, a1.y);
        a1.z = fmaf(w1, f1.z, a1.z); a1.w = fmaf(w1, f1.w, a1.w);
        a2.x = fmaf(w2, f2.x, a2.x); a2.y = fmaf(w2, f2.y, a2.y);
        a2.z = fmaf(w2, f2.z, a2.z); a2.w = fmaf(w2, f2.w, a2.w);
        a3.x = fmaf(w3, f3.x, a3.x); a3.y = fmaf(w3, f3.y, a3.y);
        a3.z = fmaf(w3, f3.z, a3.z); a3.w = fmaf(w3, f3.w, a3.w);
    }
    for (; e < end; ++e) {
        int2 ee = csr[e];
        ushort4 gg = *(const ushort4*)&yin[(size_t)ee.x * 64 + s4];
        float ww = __int_as_float(ee.y);
        float4 ff = b4f(gg);
        a0.x = fmaf(ww, ff.x, a0.x); a0.y = fmaf(ww, ff.y, a0.y);
        a0.z = fmaf(ww, ff.z, a0.z); a0.w = fmaf(ww, ff.w, a0.w);
    }
    size_t idx = (size_t)c * 64 + s4;
    float4 self = b4f(*(const ushort4*)&yin[idx]);
    float dc2 = dc * dc;
    float4 r;
    r.x = dc2 * (((a0.x + a1.x) + (a2.x + a3.x)) + self.x);
    r.y = dc2 * (((a0.y + a1.y) + (a2.y + a3.y)) + self.y);
    r.z = dc2 * (((a0.z + a1.z) + (a2.z + a3.z)) + self.z);
    r.w = dc2 * (((a0.w + a1.w) + (a2.w + a3.w)) + self.w);
    *(ushort4*)&yout[idx] = make_ushort4(f2b(r.x), f2b(r.y), f2b(r.z), f2b(r.w));
    if (use_acc) {
        float4* ap = (float4*)&acc[idx];
        float4 av = *ap;
        av.x += r.x; av.y += r.y; av.z += r.z; av.w += r.w;
        *ap = av;
    }
}

// ---------------- epilogue A: l2norm(acc)  (acc fp32, may alias out) ----------------
__global__ void k_final_acc(const float* __restrict__ acc, float* __restrict__ out) {
    int lane = threadIdx.x & 63;
    int c = (blockIdx.x * 256 + threadIdx.x) >> 6;
    if (c >= N_CNT) return;
    int idx = c * 64 + lane;
    float v = acc[idx];
    float ss = v * v;
    #pragma unroll
    for (int m = 32; m >= 1; m >>= 1) ss += __shfl_xor(ss, m, 64);
    out[idx] = v / fmaxf(sqrtf(ss), 1e-12f);
}

// ---------------- epilogue B: l2norm(y0+y1+y2+y3), all bf16 ----------------
__global__ void k_final_sum(const ubf* __restrict__ y0, const ubf* __restrict__ y1,
                            const ubf* __restrict__ y2, const ubf* __restrict__ y3,
                            float* __restrict__ out) {
    int lane = threadIdx.x & 63;
    int c = (blockIdx.x * 256 + threadIdx.x) >> 6;
    if (c >= N_CNT) return;
    int idx = c * 64 + lane;
    float v = b2f(y0[idx]) + b2f(y1[idx]) + b2f(y2[idx]) + b2f(y3[idx]);
    float ss = v * v;
    #pragma unroll
    for (int m = 32; m >= 1; m >>= 1) ss += __shfl_xor(ss, m, 64);
    out[idx] = v / fmaxf(sqrtf(ss), 1e-12f);
}

extern "C" void kernel_launch(void* const* d_in, const int* in_sizes, int n_in,
                              void* d_out, int out_size, void* d_ws, size_t ws_size,
                              hipStream_t stream) {
    const int*   edge_src   = (const int*)  d_in[0];
    const int*   edge_dst   = (const int*)  d_in[1];
    const float* edge_attr  = (const float*)d_in[2];
    const float* user_w     = (const float*)d_in[3];
    const float* artist_w   = (const float*)d_in[4];
    const float* album_w    = (const float*)d_in[5];
    const float* item_audio = (const float*)d_in[6];
    const int*   artist_ids = (const int*)  d_in[7];
    const int*   album_ids  = (const int*)  d_in[8];
    const float* Wp         = (const float*)d_in[9];
    const float* bp         = (const float*)d_in[10];
    const float* W1         = (const float*)d_in[11];
    const float* b1         = (const float*)d_in[12];
    const float* W2         = (const float*)d_in[13];
    const float* b2         = (const float*)d_in[14];

    char* p = (char*)d_ws;
    auto carve = [&](size_t bytes) -> void* {
        void* q = (void*)p;
        p += (bytes + 255) & ~(size_t)255;
        return q;
    };
    // common carve (~28 MB)
    float* dis    = (float*)carve((size_t)N_CNT * 4);
    int2*  wr     = (int2*) carve((size_t)E_CNT * 8);       // {w, rank_s|rank_d<<16}
    int*   cnt    = (int*)  carve((size_t)N_CNT * 4);
    int*   offs   = (int*)  carve((size_t)(N_CNT + 1) * 4);
    int*   incl   = (int*)  carve((size_t)N_CNT * 4);
    int*   bsums  = (int*)  carve((size_t)NB_SCAN * 4);
    int*   bbase  = (int*)  carve((size_t)NB_SCAN * 4);
    int2*  csr    = (int2*) carve((size_t)2 * E_CNT * 8);
    const size_t YB = (size_t)N_CNT * 64 * 2;      // 38.4 MB per bf16 y buffer
    size_t used = (size_t)(p - (char*)d_ws);
    // Path B (no acc RMW) needs y0..y3 bf16 in ws; else ping-pong + fp32 acc in d_out.
    int no_acc = (ws_size >= used + 4 * YB + (size_t)4096) ? 1 : 0;
    ubf *y0, *y1, *y2, *y3;
    float* acc = nullptr;
    if (no_acc) {
        y0 = (ubf*)carve(YB);
        y1 = (ubf*)carve(YB);
        y2 = (ubf*)carve(YB);
        y3 = (ubf*)carve(YB);
    } else {
        y0 = (ubf*)carve(YB);
        y1 = (ubf*)carve(YB);
        y2 = y0;
        y3 = y1;
        acc = (float*)d_out;           // fp32 accumulator lives in d_out
    }
    (void)in_sizes; (void)n_in; (void)out_size;

    hipMemsetAsync(cnt, 0, (size_t)N_CNT * 4, stream);
    k_edge_mlp<<<NB_E, 256, 0, stream>>>(edge_src, edge_dst, edge_attr,
                                         W1, b1, W2, b2, wr, cnt);
    k_scan1  <<<NB_SCAN, 256, 0, stream>>>(cnt, incl, bsums);
    k_scan2  <<<1, 256, 0, stream>>>(bsums, bbase, NB_SCAN);
    k_scan3  <<<NB_SCAN, 256, 0, stream>>>(incl, cnt, bbase, offs);
    k_scatter<<<NB_E, 256, 0, stream>>>(edge_src, edge_dst, wr, offs, csr);
    k_deg    <<<NB_SCAN, 256, 0, stream>>>(offs, csr, dis);
    k_users  <<<1024, 256, 0, stream>>>(user_w, dis, y0, acc, no_acc ? 0 : 1);
    k_items  <<<NB_I, 256, 0, stream>>>(item_audio, artist_w, album_w,
                                        artist_ids, album_ids, Wp, bp, dis,
                                        y0 + (size_t)U_CNT * 64,
                                        no_acc ? nullptr : acc + (size_t)U_CNT * 64,
                                        no_acc ? 0 : 1);
    // 4 nodes per wave -> N/4 waves -> N/16 blocks of 256
    const int PROP_BLKS = N_CNT / 16;    // 18750
    if (no_acc) {
        k_prop<<<PROP_BLKS, 256, 0, stream>>>(offs, csr, dis, y0, y1, nullptr, 0);
        k_prop<<<PROP_BLKS, 256, 0, stream>>>(offs, csr, dis, y1, y2, nullptr, 0);
        k_prop<<<PROP_BLKS, 256, 0, stream>>>(offs, csr, dis, y2, y3, nullptr, 0);
        k_final_sum<<<N_CNT / 4, 256, 0, stream>>>(y0, y1, y2, y3, (float*)d_out);
    } else {
        // y0 -> y1 -> y0 -> y1 (bf16), accumulating fp32 into acc (= d_out)
        k_prop<<<PROP_BLKS, 256, 0, stream>>>(offs, csr, dis, y0, y1, acc, 1);
        k_prop<<<PROP_BLKS, 256, 0, stream>>>(offs, csr, dis, y1, y0, acc, 1);
        k_prop<<<PROP_BLKS, 256, 0, stream>>>(offs, csr, dis, y0, y1, acc, 1);
        k_final_acc<<<N_CNT / 4, 256, 0, stream>>>(acc, (float*)d_out);
    }
}

// Round 8
// 615.666 us; speedup vs baseline: 1.1491x; 1.0320x over previous
//
#include <hip/hip_runtime.h>
#include <hip/hip_bf16.h>

#define U_CNT 200000
#define I_CNT 100000
#define N_CNT 300000
#define E_CNT 1000000
#define ATTR_D 8
#define H_DIM 32
#define NB_SCAN ((N_CNT + 255) / 256)
#define NB_E ((E_CNT + 255) / 256)
#define IB 128                               // items per item-block
#define NB_I ((I_CNT + IB - 1) / IB)         // 782 item blocks
#define NB_META (I_CNT / 16)                 // 6250 blocks, 16 items/block
#define XP 130                               // sXT pitch (bf16 elems): odd*2 -> ~2-way staging

// NOTE (rounds 1-4): all float inputs and the output are FLOAT32. absmax floor
// 1.95e-3 == bf16 rounding of the *reference*; threshold 1.26e-2.
// NOTE (round 7): rank-capture scatter + y-space reform. 1098 -> 951 us.
// NOTE (round 8): k_items register-blocked LDS GEMM. 951 -> 886 us.
// NOTE (round 9): bf16 y-storage. FETCH halved but only -9% -> latency-bound.
// NOTE (round 10): k_prop 4 nodes/wave, 16 lanes/node (4x in-flight gathers).
// 830 -> 634 us. GATHER kernels = latency x concurrency.
// NOTE (round 11): k_front fusion REGRESSED (LDS throttled atomic occupancy).
// NOTE (round 12): 4-edges/thread REGRESSED for ATOMIC kernels (line-granular
// atomic traffic + grid too small). Atomics want many waves, not batching.
// NOTE (round 13): reverted; k_items STILL ~95us in both fp32 and bf16 forms
// -> not LDS-pipe. Real cause: serial meta-gather loop in-block (1 row per
// vmem instr, behind __syncthreads, 2-3 blk/CU) = latency-bound.
// NOTE (round 14, this round): split k_meta out (4 items/wave, 16 lanes/item
// = 4 rows per vmem instr, no LDS/barrier) writing metabuf[I][64] bf16
// (same rounding as before); k_items becomes pure-streaming GEMM staged from
// audio+metabuf; sXT pitch 130 kills staging write conflicts.

typedef unsigned short ubf;

__device__ __forceinline__ float b2f(ubf b) {
    return __uint_as_float((unsigned)b << 16);
}
__device__ __forceinline__ ubf f2b(float v) {
    unsigned u = __float_as_uint(v);
    u += 0x7fffu + ((u >> 16) & 1u);           // round to nearest even
    return (ubf)(u >> 16);
}
__device__ __forceinline__ unsigned pk2(float lo, float hi) {
    return (unsigned)f2b(lo) | ((unsigned)f2b(hi) << 16);
}
__device__ __forceinline__ float4 b4f(ushort4 u) {
    return make_float4(b2f(u.x), b2f(u.y), b2f(u.z), b2f(u.w));
}

// ---------------- edge MLP + count histogram; rank capture (1 edge/thread) ----------------
__global__ void k_edge_mlp(const int* __restrict__ src, const int* __restrict__ dst,
                           const float* __restrict__ attr,
                           const float* __restrict__ W1, const float* __restrict__ b1,
                           const float* __restrict__ W2, const float* __restrict__ b2,
                           int2* __restrict__ wr, int* __restrict__ cnt) {
    __shared__ float sW1[ATTR_D * H_DIM];
    __shared__ float sb1[H_DIM];
    __shared__ float sW2[H_DIM];
    __shared__ float sb2;
    int t = threadIdx.x;
    sW1[t] = W1[t];                      // blockDim==256==ATTR_D*H_DIM
    if (t < H_DIM) { sb1[t] = b1[t]; sW2[t] = W2[t]; }
    if (t == 0) sb2 = b2[0];
    __syncthreads();
    int e = blockIdx.x * 256 + t;
    if (e >= E_CNT) return;
    const float4* a4 = (const float4*)attr;     // 32B/row: two float4
    float4 r0 = a4[e * 2 + 0];
    float4 r1 = a4[e * 2 + 1];
    float a[8] = {r0.x, r0.y, r0.z, r0.w, r1.x, r1.y, r1.z, r1.w};
    float z = sb2;
    #pragma unroll
    for (int h = 0; h < H_DIM; ++h) {
        float acc = sb1[h];
        #pragma unroll
        for (int k = 0; k < 8; ++k) acc = fmaf(a[k], sW1[k * H_DIM + h], acc);
        acc = fmaxf(acc, 0.0f);
        z = fmaf(acc, sW2[h], z);
    }
    float w = 1.0f / (1.0f + __expf(-z));
    w = fmaxf(w, 1e-6f);
    int s = src[e], d = U_CNT + dst[e];
    int rs = atomicAdd(&cnt[s], 1);      // rank of e within node s's list
    int rd = atomicAdd(&cnt[d], 1);      // rank of e within node d's list
    wr[e] = make_int2(__float_as_int(w), rs | (rd << 16));   // deg << 65536
}

// ---------------- exclusive scan of cnt -> offs (3 kernels) ----------------
__global__ void k_scan1(const int* __restrict__ cnt, int* __restrict__ incl,
                        int* __restrict__ bsums) {
    __shared__ int s[256];
    int t = threadIdx.x;
    int i = blockIdx.x * 256 + t;
    int v = (i < N_CNT) ? cnt[i] : 0;
    s[t] = v;
    __syncthreads();
    #pragma unroll
    for (int off = 1; off < 256; off <<= 1) {
        int x = (t >= off) ? s[t - off] : 0;
        __syncthreads();
        s[t] += x;
        __syncthreads();
    }
    if (i < N_CNT) incl[i] = s[t];
    if (t == 255) bsums[blockIdx.x] = s[255];
}

__global__ void k_scan2(const int* __restrict__ bsums, int* __restrict__ bbase, int nb) {
    __shared__ int s[256];
    __shared__ int carry_s;
    int t = threadIdx.x;
    if (t == 0) carry_s = 0;
    __syncthreads();
    for (int start = 0; start < nb; start += 256) {
        int i = start + t;
        int v = (i < nb) ? bsums[i] : 0;
        s[t] = v;
        __syncthreads();
        #pragma unroll
        for (int off = 1; off < 256; off <<= 1) {
            int x = (t >= off) ? s[t - off] : 0;
            __syncthreads();
            s[t] += x;
            __syncthreads();
        }
        int carry = carry_s;
        if (i < nb) bbase[i] = carry + s[t] - v;  // exclusive
        __syncthreads();
        if (t == 255) carry_s += s[255];
        __syncthreads();
    }
}

__global__ void k_scan3(const int* __restrict__ incl, const int* __restrict__ cnt,
                        const int* __restrict__ bbase, int* __restrict__ offs) {
    int i = blockIdx.x * 256 + threadIdx.x;
    if (i < N_CNT) offs[i] = bbase[blockIdx.x] + incl[i] - cnt[i];
    if (i == 0) offs[N_CNT] = 2 * E_CNT;
}

// ---------------- scatter edges into CSR at offs[node]+rank (1 edge/thread) ----------------
__global__ void k_scatter(const int* __restrict__ src, const int* __restrict__ dst,
                          const int2* __restrict__ wr, const int* __restrict__ offs,
                          int2* __restrict__ csr) {
    int e = blockIdx.x * 256 + threadIdx.x;
    if (e >= E_CNT) return;
    int2 v = wr[e];
    unsigned rk = (unsigned)v.y;
    int s = src[e], d = U_CNT + dst[e];
    csr[offs[s] + (rk & 0xffffu)] = make_int2(d, v.x);   // row under s, partner d
    csr[offs[d] + (rk >> 16)]     = make_int2(s, v.x);   // row under d, partner s
}

// ---------------- deg via segment sum (no atomics), dis = rsqrt(1+sum) ----------------
__global__ void k_deg(const int* __restrict__ offs, const int2* __restrict__ csr,
                      float* __restrict__ dis) {
    int i = blockIdx.x * 256 + threadIdx.x;
    if (i >= N_CNT) return;
    int b = offs[i], e = offs[i + 1];
    float s = 1.0f;                      // self loop weight
    for (int k = b; k < e; ++k) s += __int_as_float(csr[k].y);
    dis[i] = rsqrtf(s);                  // s >= 1 always
}

// ---------------- users: y0 = dis * l2norm(user_w) ----------------
__global__ void k_users(const float* __restrict__ user_w, const float* __restrict__ dis,
                        ubf* __restrict__ y0, float* __restrict__ acc, int use_acc) {
    int lane = threadIdx.x & 63;
    int wv = (blockIdx.x * blockDim.x + threadIdx.x) >> 6;
    int nw = (gridDim.x * blockDim.x) >> 6;
    for (int r = wv; r < U_CNT; r += nw) {
        int idx = r * 64 + lane;
        float v = user_w[idx];
        float ss = v * v;
        #pragma unroll
        for (int m = 32; m >= 1; m >>= 1) ss += __shfl_xor(ss, m, 64);
        float inv = dis[r] / fmaxf(sqrtf(ss), 1e-12f);
        float o = v * inv;
        y0[idx] = f2b(o);
        if (use_acc) acc[idx] = o;
    }
}

// ---------------- meta gather: 4 items/wave, 16 lanes/item, float4/lane ----------------
// metabuf[i][f] = bf16(art[aid[i]][f] + alb[alid[i]][f]); one vmem instr = 4 rows.
__global__ void k_meta(const float* __restrict__ art, const float* __restrict__ alb,
                       const int* __restrict__ aid, const int* __restrict__ alid,
                       ubf* __restrict__ metabuf) {
    int t = threadIdx.x;
    int lane = t & 63;
    int g = lane >> 4;                   // item group 0..3
    int q = lane & 15;                   // float4 slot within 256B row
    int wv = (blockIdx.x * 256 + t) >> 6;
    int it = wv * 4 + g;                 // exact: NB_META*4 waves * 4 = I_CNT
    if (it >= I_CNT) return;
    int a_ = aid[it], al_ = alid[it];
    float4 va = *(const float4*)&art[(size_t)a_ * 64 + q * 4];
    float4 vb = *(const float4*)&alb[(size_t)al_ * 64 + q * 4];
    ushort4 o = make_ushort4(f2b(va.x + vb.x), f2b(va.y + vb.y),
                             f2b(va.z + vb.z), f2b(va.w + vb.w));
    *(ushort4*)&metabuf[(size_t)it * 64 + q * 4] = o;
}

// ---------------- items: pure-streaming bf16-LDS GEMM, 4 items x 8 outs ----------------
// sXT [128 f][XP=130 pitch] bf16 (33.3KB) + sW [128 k][64 d] bf16 (16KB) = 48.5KB
__global__ void __launch_bounds__(256)
k_items(const float* __restrict__ audio, const ubf* __restrict__ metabuf,
        const float* __restrict__ Wp, const float* __restrict__ bp,
        const float* __restrict__ dis,
        ubf* __restrict__ yitem, float* __restrict__ accitem, int use_acc) {
    __shared__ __align__(16) ubf sXT[128 * XP];
    __shared__ __align__(16) ubf sW[128 * 64];
    int t = threadIdx.x;
    int base = blockIdx.x * IB;
    // stage Wp -> bf16
    {
        const float4* wg = (const float4*)Wp;
        #pragma unroll
        for (int r = 0; r < 8; ++r) {
            int idx = r * 256 + t;
            float4 v = wg[idx];
            ushort4 o = make_ushort4(f2b(v.x), f2b(v.y), f2b(v.z), f2b(v.w));
            *(ushort4*)&sW[idx * 4] = o;
        }
    }
    // stage audio -> sXT[f][i] transposed (streaming, coalesced)
    {
        const float4* g = (const float4*)audio + (size_t)base * 16;
        #pragma unroll
        for (int r = 0; r < 8; ++r) {
            int idx = r * 256 + t;               // 0..2047
            int i = idx >> 4, fq = idx & 15;
            float4 v = make_float4(0.f, 0.f, 0.f, 0.f);
            if (base + i < I_CNT) v = g[idx];
            sXT[(4 * fq + 0) * XP + i] = f2b(v.x);
            sXT[(4 * fq + 1) * XP + i] = f2b(v.y);
            sXT[(4 * fq + 2) * XP + i] = f2b(v.z);
            sXT[(4 * fq + 3) * XP + i] = f2b(v.w);
        }
    }
    // stage metabuf -> sXT[64+f][i] (streaming, coalesced uint4 = 8 bf16)
    {
        const uint4* m4 = (const uint4*)(metabuf + (size_t)base * 64);
        #pragma unroll
        for (int r = 0; r < 4; ++r) {
            int idx = r * 256 + t;               // 0..1023
            int i = idx >> 3, c = idx & 7;
            uint4 m = make_uint4(0u, 0u, 0u, 0u);
            if (base + i < I_CNT) m = m4[idx];
            ubf* dp = &sXT[(64 + 8 * c) * XP + i];
            dp[0 * XP] = (ubf)(m.x & 0xffffu); dp[1 * XP] = (ubf)(m.x >> 16);
            dp[2 * XP] = (ubf)(m.y & 0xffffu); dp[3 * XP] = (ubf)(m.y >> 16);
            dp[4 * XP] = (ubf)(m.z & 0xffffu); dp[5 * XP] = (ubf)(m.z >> 16);
            dp[6 * XP] = (ubf)(m.w & 0xffffu); dp[7 * XP] = (ubf)(m.w >> 16);
        }
    }
    __syncthreads();
    int og = t & 7;                      // outs 8og..8og+7
    int igr = t >> 3;                    // items 4igr..4igr+3
    float c[4][8];
    {
        float bv[8];
        #pragma unroll
        for (int j = 0; j < 8; ++j) bv[j] = bp[8 * og + j];
        #pragma unroll
        for (int i = 0; i < 4; ++i)
            #pragma unroll
            for (int j = 0; j < 8; ++j) c[i][j] = bv[j];
    }
    const ubf* xcol = &sXT[4 * igr];
    const ubf* wrow = &sW[8 * og];
    #pragma unroll 2
    for (int k = 0; k < 128; ++k) {
        ushort4 xu = *(const ushort4*)&xcol[k * XP];
        uint4 wu = *(const uint4*)&wrow[k * 64];
        float x[4] = {b2f(xu.x), b2f(xu.y), b2f(xu.z), b2f(xu.w)};
        float w[8];
        w[0] = __uint_as_float(wu.x << 16); w[1] = __uint_as_float(wu.x & 0xffff0000u);
        w[2] = __uint_as_float(wu.y << 16); w[3] = __uint_as_float(wu.y & 0xffff0000u);
        w[4] = __uint_as_float(wu.z << 16); w[5] = __uint_as_float(wu.z & 0xffff0000u);
        w[6] = __uint_as_float(wu.w << 16); w[7] = __uint_as_float(wu.w & 0xffff0000u);
        #pragma unroll
        for (int i = 0; i < 4; ++i)
            #pragma unroll
            for (int j = 0; j < 8; ++j) c[i][j] = fmaf(x[i], w[j], c[i][j]);
    }
    #pragma unroll
    for (int i = 0; i < 4; ++i) {
        float ss = 0.f;
        #pragma unroll
        for (int j = 0; j < 8; ++j) ss += c[i][j] * c[i][j];
        ss += __shfl_xor(ss, 1, 64);
        ss += __shfl_xor(ss, 2, 64);
        ss += __shfl_xor(ss, 4, 64);
        int it = base + 4 * igr + i;
        if (it < I_CNT) {
            float q = dis[U_CNT + it] / fmaxf(sqrtf(ss), 1e-12f);
            uint4 o;
            o.x = pk2(c[i][0] * q, c[i][1] * q);
            o.y = pk2(c[i][2] * q, c[i][3] * q);
            o.z = pk2(c[i][4] * q, c[i][5] * q);
            o.w = pk2(c[i][6] * q, c[i][7] * q);
            *(uint4*)&yitem[(size_t)it * 64 + 8 * og] = o;
            if (use_acc) {
                float4* ap = (float4*)&accitem[(size_t)it * 64 + 8 * og];
                ap[0] = make_float4(c[i][0] * q, c[i][1] * q, c[i][2] * q, c[i][3] * q);
                ap[1] = make_float4(c[i][4] * q, c[i][5] * q, c[i][6] * q, c[i][7] * q);
            }
        }
    }
}

// ---------------- LGConv round: 4 nodes/wave, 16 lanes/node, ushort4/lane ----------------
__global__ void k_prop(const int* __restrict__ offs, const int2* __restrict__ csr,
                       const float* __restrict__ dis,
                       const ubf* __restrict__ yin, ubf* __restrict__ yout,
                       float* __restrict__ acc, int use_acc) {
    int lane = threadIdx.x & 63;
    int g = lane >> 4;                   // node group 0..3
    int s4 = (lane & 15) * 4;            // dims s4..s4+3
    int wv = (blockIdx.x * 256 + threadIdx.x) >> 6;
    int c = wv * 4 + g;
    if (c >= N_CNT) return;
    int e = offs[c], end = offs[c + 1];
    float dc = dis[c];
    float4 a0 = make_float4(0.f, 0.f, 0.f, 0.f);
    float4 a1 = a0, a2 = a0, a3 = a0;
    for (; e + 3 < end; e += 4) {
        int2 e0 = csr[e], e1 = csr[e + 1], e2 = csr[e + 2], e3 = csr[e + 3];
        ushort4 g0 = *(const ushort4*)&yin[(size_t)e0.x * 64 + s4];
        ushort4 g1 = *(const ushort4*)&yin[(size_t)e1.x * 64 + s4];
        ushort4 g2 = *(const ushort4*)&yin[(size_t)e2.x * 64 + s4];
        ushort4 g3 = *(const ushort4*)&yin[(size_t)e3.x * 64 + s4];
        float w0 = __int_as_float(e0.y), w1 = __int_as_float(e1.y);
        float w2 = __int_as_float(e2.y), w3 = __int_as_float(e3.y);
        float4 f0 = b4f(g0), f1 = b4f(g1), f2 = b4f(g2), f3 = b4f(g3);
        a0.x = fmaf(w0, f0.x, a0.x); a0.y = fmaf(w0, f0.y, a0.y);
        a0.z = fmaf(w0, f0.z, a0.z); a0.w = fmaf(w0, f0.w, a0.w);
        a1.x = fmaf(w1, f1.x, a1.x); a1.y = fmaf(w1, f1.y, a1.y);
        a1.z = fmaf(w1, f1.z, a1.z); a1.w = fmaf(w1, f1.w, a1.w);
        a2.x = fmaf(w2, f2.x, a2.x); a2.y = fmaf(w2, f2.y, a2.y);
        a2.z = fmaf(w2, f2.z, a2.z); a2.w = fmaf(w2, f2.w, a2.w);
        a3.x = fmaf(w3, f3.x, a3.x); a3.y = fmaf(w3, f3.y, a3.y);
        a3.z = fmaf(w3, f3.z, a3.z); a3.w = fmaf(w3, f3.w, a3.w);
    }
    for (; e < end; ++e) {
        int2 ee = csr[e];
        ushort4 gg = *(const ushort4*)&yin[(size_t)ee.x * 64 + s4];
        float ww = __int_as_float(ee.y);
        float4 ff = b4f(gg);
        a0.x = fmaf(ww, ff.x, a0.x); a0.y = fmaf(ww, ff.y, a0.y);
        a0.z = fmaf(ww, ff.z, a0.z); a0.w = fmaf(ww, ff.w, a0.w);
    }
    size_t idx = (size_t)c * 64 + s4;
    float4 self = b4f(*(const ushort4*)&yin[idx]);
    float dc2 = dc * dc;
    float4 r;
    r.x = dc2 * (((a0.x + a1.x) + (a2.x + a3.x)) + self.x);
    r.y = dc2 * (((a0.y + a1.y) + (a2.y + a3.y)) + self.y);
    r.z = dc2 * (((a0.z + a1.z) + (a2.z + a3.z)) + self.z);
    r.w = dc2 * (((a0.w + a1.w) + (a2.w + a3.w)) + self.w);
    *(ushort4*)&yout[idx] = make_ushort4(f2b(r.x), f2b(r.y), f2b(r.z), f2b(r.w));
    if (use_acc) {
        float4* ap = (float4*)&acc[idx];
        float4 av = *ap;
        av.x += r.x; av.y += r.y; av.z += r.z; av.w += r.w;
        *ap = av;
    }
}

// ---------------- epilogue A: l2norm(acc)  (acc fp32, may alias out) ----------------
__global__ void k_final_acc(const float* __restrict__ acc, float* __restrict__ out) {
    int lane = threadIdx.x & 63;
    int c = (blockIdx.x * 256 + threadIdx.x) >> 6;
    if (c >= N_CNT) return;
    int idx = c * 64 + lane;
    float v = acc[idx];
    float ss = v * v;
    #pragma unroll
    for (int m = 32; m >= 1; m >>= 1) ss += __shfl_xor(ss, m, 64);
    out[idx] = v / fmaxf(sqrtf(ss), 1e-12f);
}

// ---------------- epilogue B: l2norm(y0+y1+y2+y3), all bf16 ----------------
__global__ void k_final_sum(const ubf* __restrict__ y0, const ubf* __restrict__ y1,
                            const ubf* __restrict__ y2, const ubf* __restrict__ y3,
                            float* __restrict__ out) {
    int lane = threadIdx.x & 63;
    int c = (blockIdx.x * 256 + threadIdx.x) >> 6;
    if (c >= N_CNT) return;
    int idx = c * 64 + lane;
    float v = b2f(y0[idx]) + b2f(y1[idx]) + b2f(y2[idx]) + b2f(y3[idx]);
    float ss = v * v;
    #pragma unroll
    for (int m = 32; m >= 1; m >>= 1) ss += __shfl_xor(ss, m, 64);
    out[idx] = v / fmaxf(sqrtf(ss), 1e-12f);
}

extern "C" void kernel_launch(void* const* d_in, const int* in_sizes, int n_in,
                              void* d_out, int out_size, void* d_ws, size_t ws_size,
                              hipStream_t stream) {
    const int*   edge_src   = (const int*)  d_in[0];
    const int*   edge_dst   = (const int*)  d_in[1];
    const float* edge_attr  = (const float*)d_in[2];
    const float* user_w     = (const float*)d_in[3];
    const float* artist_w   = (const float*)d_in[4];
    const float* album_w    = (const float*)d_in[5];
    const float* item_audio = (const float*)d_in[6];
    const int*   artist_ids = (const int*)  d_in[7];
    const int*   album_ids  = (const int*)  d_in[8];
    const float* Wp         = (const float*)d_in[9];
    const float* bp         = (const float*)d_in[10];
    const float* W1         = (const float*)d_in[11];
    const float* b1         = (const float*)d_in[12];
    const float* W2         = (const float*)d_in[13];
    const float* b2         = (const float*)d_in[14];

    char* p = (char*)d_ws;
    auto carve = [&](size_t bytes) -> void* {
        void* q = (void*)p;
        p += (bytes + 255) & ~(size_t)255;
        return q;
    };
    // common carve (~41 MB)
    float* dis    = (float*)carve((size_t)N_CNT * 4);
    int2*  wr     = (int2*) carve((size_t)E_CNT * 8);       // {w, rank_s|rank_d<<16}
    int*   cnt    = (int*)  carve((size_t)N_CNT * 4);
    int*   offs   = (int*)  carve((size_t)(N_CNT + 1) * 4);
    int*   incl   = (int*)  carve((size_t)N_CNT * 4);
    int*   bsums  = (int*)  carve((size_t)NB_SCAN * 4);
    int*   bbase  = (int*)  carve((size_t)NB_SCAN * 4);
    int2*  csr    = (int2*) carve((size_t)2 * E_CNT * 8);
    ubf*   metabuf= (ubf*)  carve((size_t)I_CNT * 64 * 2);  // 12.8 MB bf16
    const size_t YB = (size_t)N_CNT * 64 * 2;      // 38.4 MB per bf16 y buffer
    size_t used = (size_t)(p - (char*)d_ws);
    // Path B (no acc RMW) needs y0..y3 bf16 in ws; else ping-pong + fp32 acc in d_out.
    int no_acc = (ws_size >= used + 4 * YB + (size_t)4096) ? 1 : 0;
    ubf *y0, *y1, *y2, *y3;
    float* acc = nullptr;
    if (no_acc) {
        y0 = (ubf*)carve(YB);
        y1 = (ubf*)carve(YB);
        y2 = (ubf*)carve(YB);
        y3 = (ubf*)carve(YB);
    } else {
        y0 = (ubf*)carve(YB);
        y1 = (ubf*)carve(YB);
        y2 = y0;
        y3 = y1;
        acc = (float*)d_out;           // fp32 accumulator lives in d_out
    }
    (void)in_sizes; (void)n_in; (void)out_size;

    hipMemsetAsync(cnt, 0, (size_t)N_CNT * 4, stream);
    k_edge_mlp<<<NB_E, 256, 0, stream>>>(edge_src, edge_dst, edge_attr,
                                         W1, b1, W2, b2, wr, cnt);
    k_meta   <<<NB_META, 256, 0, stream>>>(artist_w, album_w, artist_ids,
                                           album_ids, metabuf);
    k_scan1  <<<NB_SCAN, 256, 0, stream>>>(cnt, incl, bsums);
    k_scan2  <<<1, 256, 0, stream>>>(bsums, bbase, NB_SCAN);
    k_scan3  <<<NB_SCAN, 256, 0, stream>>>(incl, cnt, bbase, offs);
    k_scatter<<<NB_E, 256, 0, stream>>>(edge_src, edge_dst, wr, offs, csr);
    k_deg    <<<NB_SCAN, 256, 0, stream>>>(offs, csr, dis);
    k_users  <<<1024, 256, 0, stream>>>(user_w, dis, y0, acc, no_acc ? 0 : 1);
    k_items  <<<NB_I, 256, 0, stream>>>(item_audio, metabuf, Wp, bp, dis,
                                        y0 + (size_t)U_CNT * 64,
                                        no_acc ? nullptr : acc + (size_t)U_CNT * 64,
                                        no_acc ? 0 : 1);
    // 4 nodes per wave -> N/4 waves -> N/16 blocks of 256
    const int PROP_BLKS = N_CNT / 16;    // 18750
    if (no_acc) {
        k_prop<<<PROP_BLKS, 256, 0, stream>>>(offs, csr, dis, y0, y1, nullptr, 0);
        k_prop<<<PROP_BLKS, 256, 0, stream>>>(offs, csr, dis, y1, y2, nullptr, 0);
        k_prop<<<PROP_BLKS, 256, 0, stream>>>(offs, csr, dis, y2, y3, nullptr, 0);
        k_final_sum<<<N_CNT / 4, 256, 0, stream>>>(y0, y1, y2, y3, (float*)d_out);
    } else {
        // y0 -> y1 -> y0 -> y1 (bf16), accumulating fp32 into acc (= d_out)
        k_prop<<<PROP_BLKS, 256, 0, stream>>>(offs, csr, dis, y0, y1, acc, 1);
        k_prop<<<PROP_BLKS, 256, 0, stream>>>(offs, csr, dis, y1, y0, acc, 1);
        k_prop<<<PROP_BLKS, 256, 0, stream>>>(offs, csr, dis, y0, y1, acc, 1);
        k_final_acc<<<N_CNT / 4, 256, 0, stream>>>(acc, (float*)d_out);
    }
}

// Round 9
// 547.450 us; speedup vs baseline: 1.2923x; 1.1246x over previous
//
#include <hip/hip_runtime.h>
#include <hip/hip_bf16.h>

#define U_CNT 200000
#define I_CNT 100000
#define N_CNT 300000
#define E_CNT 1000000
#define ATTR_D 8
#define H_DIM 32
#define NB_SCAN ((N_CNT + 255) / 256)
#define IB 128                               // items per item-block
#define NB_I ((I_CNT + IB - 1) / IB)         // 782 item blocks
#define NB_META (I_CNT / 16)                 // 6250 blocks, 16 items/block
#define XP 130                               // sXT pitch (bf16 elems)

// binning parameters
#define BSHIFT 10                            // 1024 nodes per bucket
#define NBUCK 293                            // ceil(300000/1024)
#define BCAP 12288                           // entries capacity/bucket (>20 sigma)
#define EPB 2048                             // edges per bin1 block
#define NB_BIN1 ((E_CNT + EPB - 1) / EPB)    // 489

// NOTE (rounds 1-4): all float inputs / output FLOAT32. absmax floor 1.95e-3
// == bf16 rounding of reference; threshold 1.26e-2.
// NOTE (round 7): rank-capture scatter + y-space reform. 1098 -> 951 us.
// NOTE (round 8/13/14): k_items: LDS GEMM; real fix was splitting the serial
// meta-gather into k_meta (4 rows/vmem instr). items now ~30us.
// NOTE (round 9): bf16 y-storage (FETCH/2). round 10: k_prop 4 nodes/wave
// (4x in-flight gathers) 830 -> 634. GATHERS = latency x concurrency.
// NOTE (round 11): fusion regressed (LDS throttled atomic occupancy).
// NOTE (round 12): per-thread batching regressed for ATOMICS (line-granular
// traffic). Atomics want many waves, not batching.
// NOTE (round 15, this round): CSR build rebuilt as 2-phase bucket binning.
// k_bin1 (MLP fused): LDS 293-bucket hist, 293 global atomics/block (143k
// total vs 2M), 8B packed entries (node19|partner19|w-bf16) to bucket
// regions. k_bin2 (1 block/bucket): stream entries, LDS node-hist+scan ->
// offs direct (kills scan1-3), CSR scatter L2-local with LDS ranks.
// Replaces edge_mlp(93) + scans(8) + scatter(~70). entrybuf aliases y2/y3.

typedef unsigned short ubf;

__device__ __forceinline__ float b2f(ubf b) {
    return __uint_as_float((unsigned)b << 16);
}
__device__ __forceinline__ ubf f2b(float v) {
    unsigned u = __float_as_uint(v);
    u += 0x7fffu + ((u >> 16) & 1u);           // round to nearest even
    return (ubf)(u >> 16);
}
__device__ __forceinline__ unsigned pk2(float lo, float hi) {
    return (unsigned)f2b(lo) | ((unsigned)f2b(hi) << 16);
}
__device__ __forceinline__ float4 b4f(ushort4 u) {
    return make_float4(b2f(u.x), b2f(u.y), b2f(u.z), b2f(u.w));
}
// entry pack: x = key[0:19) | (partner&0x1FFF)<<19 ; y = partner>>13 | wb<<16
__device__ __forceinline__ uint2 packE(int key, int partner, unsigned wb) {
    return make_uint2((unsigned)key | (((unsigned)partner & 0x1FFFu) << 19),
                     ((unsigned)partner >> 13) | (wb << 16));
}

// ---------------- init bucket cursors ----------------
__global__ void k_init(int* __restrict__ gcur) {
    int i = blockIdx.x * 256 + threadIdx.x;
    if (i < NBUCK) gcur[i] = i * BCAP;
}

// ---------------- phase 1: edge MLP + bucket binning ----------------
__global__ void __launch_bounds__(256)
k_bin1(const int* __restrict__ src, const int* __restrict__ dst,
       const float* __restrict__ attr,
       const float* __restrict__ W1, const float* __restrict__ b1,
       const float* __restrict__ W2, const float* __restrict__ b2,
       uint2* __restrict__ ebuf, int* __restrict__ gcur) {
    __shared__ float sW1[ATTR_D * H_DIM];
    __shared__ float sb1[H_DIM];
    __shared__ float sW2[H_DIM];
    __shared__ float sb2;
    __shared__ int hist[NBUCK];
    __shared__ int basem[NBUCK];
    int t = threadIdx.x;
    sW1[t] = W1[t];
    if (t < H_DIM) { sb1[t] = b1[t]; sW2[t] = W2[t]; }
    if (t == 0) sb2 = b2[0];
    for (int i = t; i < NBUCK; i += 256) hist[i] = 0;
    __syncthreads();
    int ebase = blockIdx.x * EPB;
    int sarr[8], darr[8];
    unsigned warr[8];
    #pragma unroll
    for (int k = 0; k < 8; ++k) {
        int e = ebase + k * 256 + t;
        sarr[k] = -1;
        if (e < E_CNT) {
            const float4* a4 = (const float4*)attr + (size_t)e * 2;
            float4 r0 = a4[0];
            float4 r1 = a4[1];
            float a[8] = {r0.x, r0.y, r0.z, r0.w, r1.x, r1.y, r1.z, r1.w};
            float z = sb2;
            #pragma unroll
            for (int h = 0; h < H_DIM; ++h) {
                float acc = sb1[h];
                #pragma unroll
                for (int kk = 0; kk < 8; ++kk) acc = fmaf(a[kk], sW1[kk * H_DIM + h], acc);
                acc = fmaxf(acc, 0.0f);
                z = fmaf(acc, sW2[h], z);
            }
            float w = 1.0f / (1.0f + __expf(-z));
            w = fmaxf(w, 1e-6f);
            int s = src[e], d = U_CNT + dst[e];
            sarr[k] = s; darr[k] = d; warr[k] = (unsigned)f2b(w);
            atomicAdd(&hist[s >> BSHIFT], 1);
            atomicAdd(&hist[d >> BSHIFT], 1);
        }
    }
    __syncthreads();
    for (int i = t; i < NBUCK; i += 256) {
        int h = hist[i];
        basem[i] = (h > 0) ? atomicAdd(&gcur[i], h) : 0;
    }
    __syncthreads();
    for (int i = t; i < NBUCK; i += 256) hist[i] = 0;   // reuse as cursor
    __syncthreads();
    #pragma unroll
    for (int k = 0; k < 8; ++k) {
        if (sarr[k] >= 0) {
            int s = sarr[k], d = darr[k];
            unsigned wb = warr[k];
            int bs = s >> BSHIFT;
            int r = atomicAdd(&hist[bs], 1);
            ebuf[(size_t)basem[bs] + r] = packE(s, d, wb);
            int bd = d >> BSHIFT;
            r = atomicAdd(&hist[bd], 1);
            ebuf[(size_t)basem[bd] + r] = packE(d, s, wb);
        }
    }
}

// ---------------- phase 2: per-bucket CSR build (offs + csr, no scans) ----------------
__global__ void __launch_bounds__(512)
k_bin2(const uint2* __restrict__ ebuf, const int* __restrict__ gcur,
       int* __restrict__ offs, int2* __restrict__ csr) {
    __shared__ int ldsCnt[NBUCK];
    __shared__ int ldsH[1024];
    __shared__ int ldsC[1024];
    __shared__ int ldsT[512];
    __shared__ int sMeta[2];          // csr_base, mycount
    int t = threadIdx.x;
    int b = blockIdx.x;
    if (t < NBUCK) ldsCnt[t] = gcur[t] - t * BCAP;
    for (int i = t; i < 1024; i += 512) { ldsH[i] = 0; ldsC[i] = 0; }
    __syncthreads();
    if (t == 0) {
        int base = 0;
        for (int i = 0; i < b; ++i) base += ldsCnt[i];
        sMeta[0] = base;
        sMeta[1] = ldsCnt[b];
    }
    __syncthreads();
    int csr_base = sMeta[0], mycount = sMeta[1];
    size_t eb = (size_t)b * BCAP;
    int first = b << BSHIFT;
    // node histogram
    for (int i = t; i < mycount; i += 512) {
        uint2 en = ebuf[eb + i];
        atomicAdd(&ldsH[(en.x & 0x7FFFFu) - first], 1);
    }
    __syncthreads();
    // exclusive scan of 1024 counters (512 threads x 2)
    int a0 = ldsH[2 * t], a1 = ldsH[2 * t + 1];
    int tot = a0 + a1;
    ldsT[t] = tot;
    __syncthreads();
    #pragma unroll
    for (int off = 1; off < 512; off <<= 1) {
        int v = (t >= off) ? ldsT[t - off] : 0;
        __syncthreads();
        ldsT[t] += v;
        __syncthreads();
    }
    int excl = ldsT[t] - tot;
    ldsH[2 * t] = excl;               // ldsH now exclusive offsets
    ldsH[2 * t + 1] = excl + a0;
    __syncthreads();
    int ncnt = min(1024, N_CNT - first);
    for (int i = t; i < ncnt; i += 512) offs[first + i] = csr_base + ldsH[i];
    if (b == NBUCK - 1 && t == 0) offs[N_CNT] = 2 * E_CNT;
    // scatter entries to final CSR (L2-local span)
    for (int i = t; i < mycount; i += 512) {
        uint2 en = ebuf[eb + i];
        int key = (int)(en.x & 0x7FFFFu);
        int partner = (int)((en.x >> 19) | ((en.y & 0xFFFFu) << 13));
        unsigned wb = en.y >> 16;
        int li = key - first;
        int r = atomicAdd(&ldsC[li], 1);
        csr[csr_base + ldsH[li] + r] = make_int2(partner, (int)(wb << 16));
    }
}

// ---------------- deg via segment sum (no atomics), dis = rsqrt(1+sum) ----------------
__global__ void k_deg(const int* __restrict__ offs, const int2* __restrict__ csr,
                      float* __restrict__ dis) {
    int i = blockIdx.x * 256 + threadIdx.x;
    if (i >= N_CNT) return;
    int b = offs[i], e = offs[i + 1];
    float s = 1.0f;                      // self loop weight
    for (int k = b; k < e; ++k) s += __int_as_float(csr[k].y);
    dis[i] = rsqrtf(s);                  // s >= 1 always
}

// ---------------- users: y0 = dis * l2norm(user_w) ----------------
__global__ void k_users(const float* __restrict__ user_w, const float* __restrict__ dis,
                        ubf* __restrict__ y0, float* __restrict__ acc, int use_acc) {
    int lane = threadIdx.x & 63;
    int wv = (blockIdx.x * blockDim.x + threadIdx.x) >> 6;
    int nw = (gridDim.x * blockDim.x) >> 6;
    for (int r = wv; r < U_CNT; r += nw) {
        int idx = r * 64 + lane;
        float v = user_w[idx];
        float ss = v * v;
        #pragma unroll
        for (int m = 32; m >= 1; m >>= 1) ss += __shfl_xor(ss, m, 64);
        float inv = dis[r] / fmaxf(sqrtf(ss), 1e-12f);
        float o = v * inv;
        y0[idx] = f2b(o);
        if (use_acc) acc[idx] = o;
    }
}

// ---------------- meta gather: 4 items/wave, 16 lanes/item, float4/lane ----------------
__global__ void k_meta(const float* __restrict__ art, const float* __restrict__ alb,
                       const int* __restrict__ aid, const int* __restrict__ alid,
                       ubf* __restrict__ metabuf) {
    int t = threadIdx.x;
    int lane = t & 63;
    int g = lane >> 4;                   // item group 0..3
    int q = lane & 15;                   // float4 slot within 256B row
    int wv = (blockIdx.x * 256 + t) >> 6;
    int it = wv * 4 + g;
    if (it >= I_CNT) return;
    int a_ = aid[it], al_ = alid[it];
    float4 va = *(const float4*)&art[(size_t)a_ * 64 + q * 4];
    float4 vb = *(const float4*)&alb[(size_t)al_ * 64 + q * 4];
    ushort4 o = make_ushort4(f2b(va.x + vb.x), f2b(va.y + vb.y),
                             f2b(va.z + vb.z), f2b(va.w + vb.w));
    *(ushort4*)&metabuf[(size_t)it * 64 + q * 4] = o;
}

// ---------------- items: pure-streaming bf16-LDS GEMM, 4 items x 8 outs ----------------
__global__ void __launch_bounds__(256)
k_items(const float* __restrict__ audio, const ubf* __restrict__ metabuf,
        const float* __restrict__ Wp, const float* __restrict__ bp,
        const float* __restrict__ dis,
        ubf* __restrict__ yitem, float* __restrict__ accitem, int use_acc) {
    __shared__ __align__(16) ubf sXT[128 * XP];
    __shared__ __align__(16) ubf sW[128 * 64];
    int t = threadIdx.x;
    int base = blockIdx.x * IB;
    // stage Wp -> bf16
    {
        const float4* wg = (const float4*)Wp;
        #pragma unroll
        for (int r = 0; r < 8; ++r) {
            int idx = r * 256 + t;
            float4 v = wg[idx];
            ushort4 o = make_ushort4(f2b(v.x), f2b(v.y), f2b(v.z), f2b(v.w));
            *(ushort4*)&sW[idx * 4] = o;
        }
    }
    // stage audio -> sXT[f][i] transposed
    {
        const float4* g = (const float4*)audio + (size_t)base * 16;
        #pragma unroll
        for (int r = 0; r < 8; ++r) {
            int idx = r * 256 + t;               // 0..2047
            int i = idx >> 4, fq = idx & 15;
            float4 v = make_float4(0.f, 0.f, 0.f, 0.f);
            if (base + i < I_CNT) v = g[idx];
            sXT[(4 * fq + 0) * XP + i] = f2b(v.x);
            sXT[(4 * fq + 1) * XP + i] = f2b(v.y);
            sXT[(4 * fq + 2) * XP + i] = f2b(v.z);
            sXT[(4 * fq + 3) * XP + i] = f2b(v.w);
        }
    }
    // stage metabuf -> sXT[64+f][i]
    {
        const uint4* m4 = (const uint4*)(metabuf + (size_t)base * 64);
        #pragma unroll
        for (int r = 0; r < 4; ++r) {
            int idx = r * 256 + t;               // 0..1023
            int i = idx >> 3, c = idx & 7;
            uint4 m = make_uint4(0u, 0u, 0u, 0u);
            if (base + i < I_CNT) m = m4[idx];
            ubf* dp = &sXT[(64 + 8 * c) * XP + i];
            dp[0 * XP] = (ubf)(m.x & 0xffffu); dp[1 * XP] = (ubf)(m.x >> 16);
            dp[2 * XP] = (ubf)(m.y & 0xffffu); dp[3 * XP] = (ubf)(m.y >> 16);
            dp[4 * XP] = (ubf)(m.z & 0xffffu); dp[5 * XP] = (ubf)(m.z >> 16);
            dp[6 * XP] = (ubf)(m.w & 0xffffu); dp[7 * XP] = (ubf)(m.w >> 16);
        }
    }
    __syncthreads();
    int og = t & 7;                      // outs 8og..8og+7
    int igr = t >> 3;                    // items 4igr..4igr+3
    float c[4][8];
    {
        float bv[8];
        #pragma unroll
        for (int j = 0; j < 8; ++j) bv[j] = bp[8 * og + j];
        #pragma unroll
        for (int i = 0; i < 4; ++i)
            #pragma unroll
            for (int j = 0; j < 8; ++j) c[i][j] = bv[j];
    }
    const ubf* xcol = &sXT[4 * igr];
    const ubf* wrow = &sW[8 * og];
    #pragma unroll 2
    for (int k = 0; k < 128; ++k) {
        ushort4 xu = *(const ushort4*)&xcol[k * XP];
        uint4 wu = *(const uint4*)&wrow[k * 64];
        float x[4] = {b2f(xu.x), b2f(xu.y), b2f(xu.z), b2f(xu.w)};
        float w[8];
        w[0] = __uint_as_float(wu.x << 16); w[1] = __uint_as_float(wu.x & 0xffff0000u);
        w[2] = __uint_as_float(wu.y << 16); w[3] = __uint_as_float(wu.y & 0xffff0000u);
        w[4] = __uint_as_float(wu.z << 16); w[5] = __uint_as_float(wu.z & 0xffff0000u);
        w[6] = __uint_as_float(wu.w << 16); w[7] = __uint_as_float(wu.w & 0xffff0000u);
        #pragma unroll
        for (int i = 0; i < 4; ++i)
            #pragma unroll
            for (int j = 0; j < 8; ++j) c[i][j] = fmaf(x[i], w[j], c[i][j]);
    }
    #pragma unroll
    for (int i = 0; i < 4; ++i) {
        float ss = 0.f;
        #pragma unroll
        for (int j = 0; j < 8; ++j) ss += c[i][j] * c[i][j];
        ss += __shfl_xor(ss, 1, 64);
        ss += __shfl_xor(ss, 2, 64);
        ss += __shfl_xor(ss, 4, 64);
        int it = base + 4 * igr + i;
        if (it < I_CNT) {
            float q = dis[U_CNT + it] / fmaxf(sqrtf(ss), 1e-12f);
            uint4 o;
            o.x = pk2(c[i][0] * q, c[i][1] * q);
            o.y = pk2(c[i][2] * q, c[i][3] * q);
            o.z = pk2(c[i][4] * q, c[i][5] * q);
            o.w = pk2(c[i][6] * q, c[i][7] * q);
            *(uint4*)&yitem[(size_t)it * 64 + 8 * og] = o;
            if (use_acc) {
                float4* ap = (float4*)&accitem[(size_t)it * 64 + 8 * og];
                ap[0] = make_float4(c[i][0] * q, c[i][1] * q, c[i][2] * q, c[i][3] * q);
                ap[1] = make_float4(c[i][4] * q, c[i][5] * q, c[i][6] * q, c[i][7] * q);
            }
        }
    }
}

// ---------------- LGConv round: 4 nodes/wave, 16 lanes/node, ushort4/lane ----------------
__global__ void k_prop(const int* __restrict__ offs, const int2* __restrict__ csr,
                       const float* __restrict__ dis,
                       const ubf* __restrict__ yin, ubf* __restrict__ yout,
                       float* __restrict__ acc, int use_acc) {
    int lane = threadIdx.x & 63;
    int g = lane >> 4;                   // node group 0..3
    int s4 = (lane & 15) * 4;            // dims s4..s4+3
    int wv = (blockIdx.x * 256 + threadIdx.x) >> 6;
    int c = wv * 4 + g;
    if (c >= N_CNT) return;
    int e = offs[c], end = offs[c + 1];
    float dc = dis[c];
    float4 a0 = make_float4(0.f, 0.f, 0.f, 0.f);
    float4 a1 = a0, a2 = a0, a3 = a0;
    for (; e + 3 < end; e += 4) {
        int2 e0 = csr[e], e1 = csr[e + 1], e2 = csr[e + 2], e3 = csr[e + 3];
        ushort4 g0 = *(const ushort4*)&yin[(size_t)e0.x * 64 + s4];
        ushort4 g1 = *(const ushort4*)&yin[(size_t)e1.x * 64 + s4];
        ushort4 g2 = *(const ushort4*)&yin[(size_t)e2.x * 64 + s4];
        ushort4 g3 = *(const ushort4*)&yin[(size_t)e3.x * 64 + s4];
        float w0 = __int_as_float(e0.y), w1 = __int_as_float(e1.y);
        float w2 = __int_as_float(e2.y), w3 = __int_as_float(e3.y);
        float4 f0 = b4f(g0), f1 = b4f(g1), f2 = b4f(g2), f3 = b4f(g3);
        a0.x = fmaf(w0, f0.x, a0.x); a0.y = fmaf(w0, f0.y, a0.y);
        a0.z = fmaf(w0, f0.z, a0.z); a0.w = fmaf(w0, f0.w, a0.w);
        a1.x = fmaf(w1, f1.x, a1.x); a1.y = fmaf(w1, f1.y, a1.y);
        a1.z = fmaf(w1, f1.z, a1.z); a1.w = fmaf(w1, f1.w, a1.w);
        a2.x = fmaf(w2, f2.x, a2.x); a2.y = fmaf(w2, f2.y, a2.y);
        a2.z = fmaf(w2, f2.z, a2.z); a2.w = fmaf(w2, f2.w, a2.w);
        a3.x = fmaf(w3, f3.x, a3.x); a3.y = fmaf(w3, f3.y, a3.y);
        a3.z = fmaf(w3, f3.z, a3.z); a3.w = fmaf(w3, f3.w, a3.w);
    }
    for (; e < end; ++e) {
        int2 ee = csr[e];
        ushort4 gg = *(const ushort4*)&yin[(size_t)ee.x * 64 + s4];
        float ww = __int_as_float(ee.y);
        float4 ff = b4f(gg);
        a0.x = fmaf(ww, ff.x, a0.x); a0.y = fmaf(ww, ff.y, a0.y);
        a0.z = fmaf(ww, ff.z, a0.z); a0.w = fmaf(ww, ff.w, a0.w);
    }
    size_t idx = (size_t)c * 64 + s4;
    float4 self = b4f(*(const ushort4*)&yin[idx]);
    float dc2 = dc * dc;
    float4 r;
    r.x = dc2 * (((a0.x + a1.x) + (a2.x + a3.x)) + self.x);
    r.y = dc2 * (((a0.y + a1.y) + (a2.y + a3.y)) + self.y);
    r.z = dc2 * (((a0.z + a1.z) + (a2.z + a3.z)) + self.z);
    r.w = dc2 * (((a0.w + a1.w) + (a2.w + a3.w)) + self.w);
    *(ushort4*)&yout[idx] = make_ushort4(f2b(r.x), f2b(r.y), f2b(r.z), f2b(r.w));
    if (use_acc) {
        float4* ap = (float4*)&acc[idx];
        float4 av = *ap;
        av.x += r.x; av.y += r.y; av.z += r.z; av.w += r.w;
        *ap = av;
    }
}

// ---------------- epilogue A: l2norm(acc)  (acc fp32, may alias out) ----------------
__global__ void k_final_acc(const float* __restrict__ acc, float* __restrict__ out) {
    int lane = threadIdx.x & 63;
    int c = (blockIdx.x * 256 + threadIdx.x) >> 6;
    if (c >= N_CNT) return;
    int idx = c * 64 + lane;
    float v = acc[idx];
    float ss = v * v;
    #pragma unroll
    for (int m = 32; m >= 1; m >>= 1) ss += __shfl_xor(ss, m, 64);
    out[idx] = v / fmaxf(sqrtf(ss), 1e-12f);
}

// ---------------- epilogue B: l2norm(y0+y1+y2+y3), all bf16 ----------------
__global__ void k_final_sum(const ubf* __restrict__ y0, const ubf* __restrict__ y1,
                            const ubf* __restrict__ y2, const ubf* __restrict__ y3,
                            float* __restrict__ out) {
    int lane = threadIdx.x & 63;
    int c = (blockIdx.x * 256 + threadIdx.x) >> 6;
    if (c >= N_CNT) return;
    int idx = c * 64 + lane;
    float v = b2f(y0[idx]) + b2f(y1[idx]) + b2f(y2[idx]) + b2f(y3[idx]);
    float ss = v * v;
    #pragma unroll
    for (int m = 32; m >= 1; m >>= 1) ss += __shfl_xor(ss, m, 64);
    out[idx] = v / fmaxf(sqrtf(ss), 1e-12f);
}

extern "C" void kernel_launch(void* const* d_in, const int* in_sizes, int n_in,
                              void* d_out, int out_size, void* d_ws, size_t ws_size,
                              hipStream_t stream) {
    const int*   edge_src   = (const int*)  d_in[0];
    const int*   edge_dst   = (const int*)  d_in[1];
    const float* edge_attr  = (const float*)d_in[2];
    const float* user_w     = (const float*)d_in[3];
    const float* artist_w   = (const float*)d_in[4];
    const float* album_w    = (const float*)d_in[5];
    const float* item_audio = (const float*)d_in[6];
    const int*   artist_ids = (const int*)  d_in[7];
    const int*   album_ids  = (const int*)  d_in[8];
    const float* Wp         = (const float*)d_in[9];
    const float* bp         = (const float*)d_in[10];
    const float* W1         = (const float*)d_in[11];
    const float* b1         = (const float*)d_in[12];
    const float* W2         = (const float*)d_in[13];
    const float* b2         = (const float*)d_in[14];

    char* p = (char*)d_ws;
    auto carve = [&](size_t bytes) -> void* {
        void* q = (void*)p;
        p += (bytes + 255) & ~(size_t)255;
        return q;
    };
    // common carve (~31 MB)
    float* dis    = (float*)carve((size_t)N_CNT * 4);
    int*   offs   = (int*)  carve((size_t)(N_CNT + 1) * 4);
    int*   gcur   = (int*)  carve((size_t)NBUCK * 4);
    int2*  csr    = (int2*) carve((size_t)2 * E_CNT * 8);
    ubf*   metabuf= (ubf*)  carve((size_t)I_CNT * 64 * 2);  // 12.8 MB bf16
    const size_t YB = (size_t)N_CNT * 64 * 2;      // 38.4 MB per bf16 y buffer
    const size_t EBUF = (size_t)NBUCK * BCAP * 8;  // 28.8 MB entry buffer
    size_t used = (size_t)(p - (char*)d_ws);
    // Path B (no acc RMW) needs y0..y3 bf16 in ws; ebuf aliases y2/y3
    // (dead before prop round 2). Else ping-pong + fp32 acc in d_out.
    int no_acc = (ws_size >= used + 4 * YB + (size_t)4096) ? 1 : 0;
    ubf *y0, *y1, *y2, *y3;
    uint2* ebuf;
    float* acc = nullptr;
    if (no_acc) {
        y0 = (ubf*)carve(YB);
        y1 = (ubf*)carve(YB);
        y2 = (ubf*)carve(YB);
        y3 = (ubf*)carve(YB);
        ebuf = (uint2*)y2;             // alias: y2+y3 = 76.8MB >= 28.8MB
    } else {
        y0 = (ubf*)carve(YB);
        y1 = (ubf*)carve(YB);
        y2 = y0;
        y3 = y1;
        acc = (float*)d_out;           // fp32 accumulator lives in d_out
        ebuf = (uint2*)carve(EBUF);
    }
    (void)in_sizes; (void)n_in; (void)out_size;

    k_init <<<2, 256, 0, stream>>>(gcur);
    k_meta <<<NB_META, 256, 0, stream>>>(artist_w, album_w, artist_ids,
                                         album_ids, metabuf);
    k_bin1 <<<NB_BIN1, 256, 0, stream>>>(edge_src, edge_dst, edge_attr,
                                         W1, b1, W2, b2, ebuf, gcur);
    k_bin2 <<<NBUCK, 512, 0, stream>>>(ebuf, gcur, offs, csr);
    k_deg  <<<NB_SCAN, 256, 0, stream>>>(offs, csr, dis);
    k_users<<<1024, 256, 0, stream>>>(user_w, dis, y0, acc, no_acc ? 0 : 1);
    k_items<<<NB_I, 256, 0, stream>>>(item_audio, metabuf, Wp, bp, dis,
                                      y0 + (size_t)U_CNT * 64,
                                      no_acc ? nullptr : acc + (size_t)U_CNT * 64,
                                      no_acc ? 0 : 1);
    // 4 nodes per wave -> N/4 waves -> N/16 blocks of 256
    const int PROP_BLKS = N_CNT / 16;    // 18750
    if (no_acc) {
        k_prop<<<PROP_BLKS, 256, 0, stream>>>(offs, csr, dis, y0, y1, nullptr, 0);
        k_prop<<<PROP_BLKS, 256, 0, stream>>>(offs, csr, dis, y1, y2, nullptr, 0);
        k_prop<<<PROP_BLKS, 256, 0, stream>>>(offs, csr, dis, y2, y3, nullptr, 0);
        k_final_sum<<<N_CNT / 4, 256, 0, stream>>>(y0, y1, y2, y3, (float*)d_out);
    } else {
        // y0 -> y1 -> y0 -> y1 (bf16), accumulating fp32 into acc (= d_out)
        k_prop<<<PROP_BLKS, 256, 0, stream>>>(offs, csr, dis, y0, y1, acc, 1);
        k_prop<<<PROP_BLKS, 256, 0, stream>>>(offs, csr, dis, y1, y0, acc, 1);
        k_prop<<<PROP_BLKS, 256, 0, stream>>>(offs, csr, dis, y0, y1, acc, 1);
        k_final_acc<<<N_CNT / 4, 256, 0, stream>>>(acc, (float*)d_out);
    }
}